// Round 6
// baseline (534.578 us; speedup 1.0000x reference)
//
#include <hip/hip_runtime.h>
#include <stdint.h>

typedef unsigned int u32;
typedef unsigned short u16;
typedef unsigned long long u64;

#define DI __device__ __forceinline__

DI float bf2f(u16 u) { union { u32 i; float f; } v; v.i = ((u32)u) << 16; return v.f; }
DI u16 f2bf(float f) {
    union { u32 i; float f; } v; v.f = f;
    u32 u = v.i;
    u32 r = (u + 0x7fffu + ((u >> 16) & 1u)) >> 16;
    return (u16)r;
}
DI float2 unpack2(u32 x) { return make_float2(bf2f((u16)(x & 0xffffu)), bf2f((u16)(x >> 16))); }
DI u32 pack2(float a, float b) { return (u32)f2bf(a) | ((u32)f2bf(b) << 16); }

DI void fma8(float* acc, float w, uint4 xv) {
    float2 f0 = unpack2(xv.x), f1 = unpack2(xv.y), f2 = unpack2(xv.z), f3 = unpack2(xv.w);
    acc[0] += w * f0.x; acc[1] += w * f0.y; acc[2] += w * f1.x; acc[3] += w * f1.y;
    acc[4] += w * f2.x; acc[5] += w * f2.y; acc[6] += w * f3.x; acc[7] += w * f3.y;
}

DI uint4 scale8(uint4 v, float s) {
    uint4 r;
    float2 f;
    f = unpack2(v.x); r.x = pack2(f.x * s, f.y * s);
    f = unpack2(v.y); r.y = pack2(f.x * s, f.y * s);
    f = unpack2(v.z); r.z = pack2(f.x * s, f.y * s);
    f = unpack2(v.w); r.w = pack2(f.x * s, f.y * s);
    return r;
}

// ---------------- pre: x->bf16 convert + mask bit array (fused) ----------------

__global__ void pre_k(const float* __restrict__ X, u16* __restrict__ Xb, int total4, int cvtBlocks,
                      const float* __restrict__ mask, u64* __restrict__ bits, int n) {
    if ((int)blockIdx.x < cvtBlocks) {
        int i = blockIdx.x * blockDim.x + threadIdx.x;
        if (i >= total4) return;
        float4 v = ((const float4*)X)[i];
        ushort4 o;
        o.x = f2bf(v.x); o.y = f2bf(v.y); o.z = f2bf(v.z); o.w = f2bf(v.w);
        ((ushort4*)Xb)[i] = o;
    } else {
        int bid = blockIdx.x - cvtBlocks;
        int i = bid * 256 + threadIdx.x;          // one mask element per thread
        bool m = (i < n) && (mask[i] != 0.f);
        u64 word = __ballot(m);
        if ((threadIdx.x & 63) == 0) {
            int widx = i >> 6;
            if (i < n) bits[widx] = word;
        }
    }
}

DI int maskbit(const u64* __restrict__ bits, int i) {
    return (int)((bits[i >> 6] >> (i & 63)) & 1);
}

// ---------------- CSR build ----------------

// one packed atomic per edge: lo16 = cnt, hi16 = cntm
__global__ void edge_stats(const int* __restrict__ ei, const u64* __restrict__ bits,
                           u32* __restrict__ cntP, int E) {
    int e = blockIdx.x * blockDim.x + threadIdx.x;
    if (e >= E) return;
    int c = ei[e];          // src (col)
    int r = ei[E + e];      // dst (row)
    if (r != c) {
        u32 add = 1u + ((u32)maskbit(bits, c) << 16);
        atomicAdd(&cntP[r], add);
    }
}

#define SCAN_B 1024
__global__ __launch_bounds__(1024) void scanA(const u32* __restrict__ cntP, int* __restrict__ rowptr,
                                              int* __restrict__ blocksum, int n) {
    __shared__ int s[SCAN_B];
    int t = threadIdx.x;
    int i = blockIdx.x * SCAN_B + t;
    int v = (i < n) ? (int)(cntP[i] & 0xffffu) : 0;
    s[t] = v; __syncthreads();
    for (int off = 1; off < SCAN_B; off <<= 1) {
        int tmp = (t >= off) ? s[t - off] : 0;
        __syncthreads();
        s[t] += tmp;
        __syncthreads();
    }
    if (i < n) rowptr[i] = s[t] - v;   // local exclusive
    if (t == SCAN_B - 1) blocksum[blockIdx.x] = s[t];
}

// merged scanB+scanC+norm: each block scans blocksums, finalizes its 1024 rows
__global__ __launch_bounds__(256) void scanBC(const int* __restrict__ blocksum, int nblk,
                                              int* __restrict__ rowptr, const u32* __restrict__ cntP,
                                              const float* __restrict__ mask,
                                              int* __restrict__ cursL, int* __restrict__ cursH,
                                              int* __restrict__ mid,
                                              float* __restrict__ dinvL, float* __restrict__ dinvH,
                                              float* __restrict__ dinvLL, float* __restrict__ dinvHH,
                                              float2* __restrict__ diag1, float2* __restrict__ diag2, int n) {
    __shared__ int s[128];
    int t = threadIdx.x;
    if (t < 128) s[t] = (t < nblk) ? blocksum[t] : 0;
    __syncthreads();
    for (int off = 1; off < 128; off <<= 1) {
        int tmp = (t >= off && t < 128) ? s[t - off] : 0;
        __syncthreads();
        if (t < 128) s[t] += tmp;
        __syncthreads();
    }
    int blockoff = (blockIdx.x == 0) ? 0 : s[blockIdx.x - 1];
    if (blockIdx.x == 0 && t == 0) rowptr[n] = s[127];
#pragma unroll
    for (int k = 0; k < 4; k++) {
        int i = blockIdx.x * SCAN_B + k * 256 + t;
        if (i >= n) break;
        int v = rowptr[i] + blockoff;
        rowptr[i] = v;
        u32 p = cntP[i];
        int ci = (int)(p & 0xffffu);
        int cmi = (int)(p >> 16);
        cursL[i] = v;
        cursH[i] = v + cmi;
        mid[i] = v + cmi;
        float c = (float)ci;
        float cm = (float)cmi;
        bool mi = mask[i] != 0.f;
        float degL = (mi ? c : 0.f) + 1.f;
        float degH = (mi ? 0.f : c) + 1.f;
        float degLL = cm + 1.f;
        float degHH = (c - cm) + 1.f;
        dinvL[i] = rsqrtf(degL);
        dinvH[i] = rsqrtf(degH);
        dinvLL[i] = rsqrtf(degLL);
        dinvHH[i] = rsqrtf(degHH);
        diag1[i] = make_float2(1.f / degL, 1.f / degH);
        diag2[i] = make_float2(1.f / degLL, 1.f / degHH);
    }
}

__global__ void scatter_edges(const int* __restrict__ ei, const u64* __restrict__ bits,
                              int* __restrict__ cursL, int* __restrict__ cursH,
                              int* __restrict__ sorted, int E) {
    int e = blockIdx.x * blockDim.x + threadIdx.x;
    if (e >= E) return;
    int c = ei[e];
    int r = ei[E + e];
    if (r != c) {
        int pos;
        if (maskbit(bits, c)) pos = atomicAdd(&cursL[r], 1);
        else                  pos = atomicAdd(&cursH[r], 1);
        sorted[pos] = c;
    }
}

// ---------------- SpMM layer 1 ----------------

__global__ __launch_bounds__(256) void spmm1(const u16* __restrict__ X,
                                             const int* __restrict__ rowptr, const int* __restrict__ sorted,
                                             const float* __restrict__ mask,
                                             const float* __restrict__ dinvL, const float* __restrict__ dinvH,
                                             const float2* __restrict__ diag1,
                                             u16* __restrict__ Yl, u16* __restrict__ Yh, int n) {
    int r = blockIdx.x * 4 + (threadIdx.x >> 6);
    if (r >= n) return;
    int lane = threadIdx.x & 63;
    int q = lane >> 4, l16 = lane & 15;
    bool mi = mask[r] != 0.f;
    const float* dinvA = mi ? dinvL : dinvH;
    float da = dinvA[r];
    float2 dg = diag1[r];
    float diag = mi ? dg.x : dg.y;

    const uint4* Xv = (const uint4*)X;
    uint4 xown = Xv[(size_t)r * 16 + l16];

    float acc[8] = {0.f, 0.f, 0.f, 0.f, 0.f, 0.f, 0.f, 0.f};
    int e0 = rowptr[r], e1 = rowptr[r + 1];
    int last = e1 - 1;
    for (int base = e0; base < e1; base += 8) {
        int s0 = base + q, s1 = base + 4 + q;
        int i0 = min(s0, last), i1 = min(s1, last);
        int c0 = sorted[i0], c1 = sorted[i1];
        float w0 = (s0 < e1) ? da * dinvA[c0] : 0.f;
        float w1 = (s1 < e1) ? da * dinvA[c1] : 0.f;
        uint4 x0 = Xv[(size_t)c0 * 16 + l16];
        uint4 x1 = Xv[(size_t)c1 * 16 + l16];
        fma8(acc, w0, x0);
        fma8(acc, w1, x1);
    }
#pragma unroll
    for (int k = 0; k < 8; k++) {
        acc[k] += __shfl_xor(acc[k], 16);
        acc[k] += __shfl_xor(acc[k], 32);
    }
    float2 o0 = unpack2(xown.x), o1 = unpack2(xown.y), o2 = unpack2(xown.z), o3 = unpack2(xown.w);
    uint4 res;
    res.x = pack2(acc[0] + diag * o0.x, acc[1] + diag * o0.y);
    res.y = pack2(acc[2] + diag * o1.x, acc[3] + diag * o1.y);
    res.z = pack2(acc[4] + diag * o2.x, acc[5] + diag * o2.y);
    res.w = pack2(acc[6] + diag * o3.x, acc[7] + diag * o3.y);
    uint4* Ya = (uint4*)(mi ? Yl : Yh);
    uint4* Yc = (uint4*)(mi ? Yh : Yl);
    if (q == 0) Ya[(size_t)r * 16 + l16] = res;
    if (q == 1) Yc[(size_t)r * 16 + l16] = xown;   // deg=1, diag=1 -> exact copy
}

// ---------------- SpMM layer 2: partitioned rows, two uniform phases ----------------

__global__ __launch_bounds__(256) void spmm2(const u16* __restrict__ XL, const u16* __restrict__ XH,
                                             const int* __restrict__ rowptr, const int* __restrict__ mid,
                                             const int* __restrict__ sorted,
                                             const float* __restrict__ dinvLL, const float* __restrict__ dinvHH,
                                             const float2* __restrict__ diag2,
                                             u16* __restrict__ Zl, u16* __restrict__ Zh, int n) {
    int r = blockIdx.x * 4 + (threadIdx.x >> 6);
    if (r >= n) return;
    int lane = threadIdx.x & 63;
    int q = lane >> 4, l16 = lane & 15;

    float dllr = dinvLL[r], dhhr = dinvHH[r];
    float2 dg = diag2[r];

    const uint4* XLv = (const uint4*)XL;
    const uint4* XHv = (const uint4*)XH;
    uint4 xlown = XLv[(size_t)r * 16 + l16];
    uint4 xhown = XHv[(size_t)r * 16 + l16];

    float accL[8] = {0.f, 0.f, 0.f, 0.f, 0.f, 0.f, 0.f, 0.f};
    float accH[8] = {0.f, 0.f, 0.f, 0.f, 0.f, 0.f, 0.f, 0.f};
    int e0 = rowptr[r], m = mid[r], e1 = rowptr[r + 1];

    int lastL = m - 1;
    for (int base = e0; base < m; base += 8) {
        int s0 = base + q, s1 = base + 4 + q;
        int i0 = min(s0, lastL), i1 = min(s1, lastL);
        int c0 = sorted[i0], c1 = sorted[i1];
        float w0 = (s0 < m) ? dllr * dinvLL[c0] : 0.f;
        float w1 = (s1 < m) ? dllr * dinvLL[c1] : 0.f;
        uint4 x0 = XLv[(size_t)c0 * 16 + l16];
        uint4 x1 = XLv[(size_t)c1 * 16 + l16];
        fma8(accL, w0, x0);
        fma8(accL, w1, x1);
    }
    int lastH = e1 - 1;
    for (int base = m; base < e1; base += 8) {
        int s0 = base + q, s1 = base + 4 + q;
        int i0 = min(s0, lastH), i1 = min(s1, lastH);
        int c0 = sorted[i0], c1 = sorted[i1];
        float w0 = (s0 < e1) ? dhhr * dinvHH[c0] : 0.f;
        float w1 = (s1 < e1) ? dhhr * dinvHH[c1] : 0.f;
        uint4 x0 = XHv[(size_t)c0 * 16 + l16];
        uint4 x1 = XHv[(size_t)c1 * 16 + l16];
        fma8(accH, w0, x0);
        fma8(accH, w1, x1);
    }
#pragma unroll
    for (int k = 0; k < 8; k++) {
        accL[k] += __shfl_xor(accL[k], 16);
        accL[k] += __shfl_xor(accL[k], 32);
        accH[k] += __shfl_xor(accH[k], 16);
        accH[k] += __shfl_xor(accH[k], 32);
    }
    float2 l0 = unpack2(xlown.x), l1 = unpack2(xlown.y), l2 = unpack2(xlown.z), l3 = unpack2(xlown.w);
    float2 h0 = unpack2(xhown.x), h1 = unpack2(xhown.y), h2 = unpack2(xhown.z), h3 = unpack2(xhown.w);
    float cl = dg.x, ch = dg.y;
    uint4 rl, rh;
    rl.x = pack2(accL[0] + cl * l0.x, accL[1] + cl * l0.y);
    rl.y = pack2(accL[2] + cl * l1.x, accL[3] + cl * l1.y);
    rl.z = pack2(accL[4] + cl * l2.x, accL[5] + cl * l2.y);
    rl.w = pack2(accL[6] + cl * l3.x, accL[7] + cl * l3.y);
    rh.x = pack2(accH[0] + ch * h0.x, accH[1] + ch * h0.y);
    rh.y = pack2(accH[2] + ch * h1.x, accH[3] + ch * h1.y);
    rh.z = pack2(accH[4] + ch * h2.x, accH[5] + ch * h2.y);
    rh.w = pack2(accH[6] + ch * h3.x, accH[7] + ch * h3.y);
    if (q == 0) ((uint4*)Zl)[(size_t)r * 16 + l16] = rl;
    if (q == 1) ((uint4*)Zh)[(size_t)r * 16 + l16] = rh;
}

// ---------------- weight transpose f32 -> bf16, lam folded into W2L/W2H ----------------

__global__ void transposeW(const float* __restrict__ W1L, const float* __restrict__ W1H,
                           const float* __restrict__ W2L, const float* __restrict__ W2H,
                           const float* __restrict__ WX,
                           const float* __restrict__ lam1, const float* __restrict__ lam2,
                           u16* __restrict__ Bt) {
    int w = blockIdx.x >> 6;                         // which weight
    int idx = (blockIdx.x & 63) * 256 + threadIdx.x; // 0..16383
    float scale = 1.f;
    if (w == 2) { float e0 = __expf(lam1[0]), e1 = __expf(lam1[1]); scale = e1 / (e0 + e1); }
    if (w == 3) { float f0 = __expf(lam2[0]), f1 = __expf(lam2[1]); scale = f1 / (f0 + f1); }
    const float* src = (w == 0) ? W1L : (w == 1) ? W1H : (w == 2) ? W2L : (w == 3) ? W2H : WX;
    int k = idx >> 7, nn = idx & 127;
    Bt[(size_t)w * 16384 + (size_t)nn * 128 + k] = f2bf(scale * src[idx]);
}

// ---------------- LDS-staged MFMA GEMM building blocks ----------------

typedef __attribute__((ext_vector_type(8))) short bf16x8;
typedef __attribute__((ext_vector_type(4))) float f32x4;

// Stage Bt (32 KB, [n][k] bf16) into LDS in MFMA-fragment order:
// frag (nt,kb) occupies 64 consecutive uint4 at (nt*4+kb)*64, indexed by lane.
DI void stageB(const uint4* __restrict__ Bt4, uint4* Bs, int tid) {
#pragma unroll
    for (int i = 0; i < 8; i++) {
        int g = i * 256 + tid;           // coalesced global read
        int nn = g >> 4, c = g & 15;     // c = kb*4+quad
        int d = ((nn >> 4) * 4 + (c >> 2)) * 64 + (c & 3) * 16 + (nn & 15);
        Bs[d] = Bt4[g];
    }
}

DI void loadA(uint4* a, const uint4* __restrict__ A4, int mr, int quad) {
#pragma unroll
    for (int kb = 0; kb < 4; kb++)
        a[kb] = A4[(size_t)mr * 16 + kb * 4 + quad];
}

DI void mfmaSec(const uint4* a, const uint4* Bs, f32x4* acc, int lane) {
#pragma unroll
    for (int nt = 0; nt < 8; nt++)
#pragma unroll
        for (int kb = 0; kb < 4; kb++) {
            bf16x8 av = *(const bf16x8*)&a[kb];
            bf16x8 bv = *(const bf16x8*)&Bs[(nt * 4 + kb) * 64 + lane];
            acc[nt] = __builtin_amdgcn_mfma_f32_16x16x32_bf16(av, bv, acc[nt], 0, 0, 0);
        }
}

// ---------------- layer-1 GEMM (2 jobs via blockIdx.y), relu, coalesced store ----------------

__global__ __launch_bounds__(256) void gemm_lds(const u16* __restrict__ A0, const u16* __restrict__ Bt0,
                                                u16* __restrict__ C0,
                                                const u16* __restrict__ A1, const u16* __restrict__ Bt1,
                                                u16* __restrict__ C1, int M) {
    __shared__ uint4 Bs[2048];   // 32 KB; reused as C bounce (needs 1024)
    const u16* A = blockIdx.y ? A1 : A0;
    const u16* Bt = blockIdx.y ? Bt1 : Bt0;
    u16* C = blockIdx.y ? C1 : C0;

    int tid = threadIdx.x;
    int wave = tid >> 6, lane = tid & 63, quad = lane >> 4, l16 = lane & 15;
    int tile = blockIdx.x * 64;
    int m0 = tile + wave * 16 + l16;
    int mr = min(m0, M - 1);

    uint4 a[4];
    loadA(a, (const uint4*)A, mr, quad);     // issued before staging: latency hidden
    stageB((const uint4*)Bt, Bs, tid);
    __syncthreads();

    f32x4 acc[8];
#pragma unroll
    for (int nt = 0; nt < 8; nt++) acc[nt] = f32x4{0.f, 0.f, 0.f, 0.f};
    mfmaSec(a, Bs, acc, lane);

    __syncthreads();                          // Bs reads done; reuse as C bounce
    u16* Cs = (u16*)Bs;
    int lrow0 = wave * 16 + quad * 4;
#pragma unroll
    for (int nt = 0; nt < 8; nt++)
#pragma unroll
        for (int rr = 0; rr < 4; rr++) {
            float v = acc[nt][rr];
            v = v > 0.f ? v : 0.f;            // relu (layer 1 only)
            Cs[(lrow0 + rr) * 128 + nt * 16 + l16] = f2bf(v);
        }
    __syncthreads();
    uint4* Cs4 = (uint4*)Bs;
    uint4* C4 = (uint4*)C;
#pragma unroll
    for (int i = 0; i < 4; i++) {
        int g = i * 256 + tid;                // 1024 uint4 = 64 rows
        int grow = tile + (g >> 4);
        if (grow < M) C4[(size_t)grow * 16 + (g & 15)] = Cs4[g];
    }
}

// ---------------- fused final: relu(Zl@BtL' + Zh@BtH' + lamx*Xb@BtX) @ lin_w + b ----------------

__global__ __launch_bounds__(256) void fused_final(const u16* __restrict__ Zl, const u16* __restrict__ Zh,
                                                   const u16* __restrict__ Xb,
                                                   const u16* __restrict__ BtL, const u16* __restrict__ BtH,
                                                   const u16* __restrict__ BtX,
                                                   const float* __restrict__ mask,
                                                   const float* __restrict__ lam1, const float* __restrict__ lam2,
                                                   const float* __restrict__ lin_w, const float* __restrict__ lin_b,
                                                   float* __restrict__ out, int M) {
    __shared__ uint4 Bs[2048];    // 32 KB, restaged per section
    __shared__ float lws[1280];   // lin_w 128x10 f32

    int tid = threadIdx.x;
    int wave = tid >> 6, lane = tid & 63, quad = lane >> 4, l16 = lane & 15;
    int tile = blockIdx.x * 64;
    int m0 = tile + wave * 16 + l16;
    int mr = min(m0, M - 1);

    // section-0 A (Zl) + lin_w staging + section-0 B staging
    uint4 a[4], an[4];
    loadA(a, (const uint4*)Zl, mr, quad);
    {
        const uint4* lw4 = (const uint4*)lin_w;
        uint4* lws4 = (uint4*)lws;
        lws4[tid] = lw4[tid];
        if (tid < 64) lws4[256 + tid] = lw4[256 + tid];
    }
    stageB((const uint4*)BtL, Bs, tid);

    // gate scalar for this lane's row (X-section pre-scale)
    float e0 = __expf(lam1[0]), e1 = __expf(lam1[1]);
    float lamxl = e0 / (e0 + e1);
    float f0 = __expf(lam2[0]), f1 = __expf(lam2[1]);
    float lamxh = f0 / (f0 + f1);
    float lamx = (mask[mr] != 0.f) ? lamxl : lamxh;

    __syncthreads();

    f32x4 acc[8];
#pragma unroll
    for (int nt = 0; nt < 8; nt++) acc[nt] = f32x4{0.f, 0.f, 0.f, 0.f};

    loadA(an, (const uint4*)Zh, mr, quad);    // prefetch section-1 A
    mfmaSec(a, Bs, acc, lane);                // section 0

    __syncthreads();
    stageB((const uint4*)BtH, Bs, tid);
#pragma unroll
    for (int kb = 0; kb < 4; kb++) a[kb] = an[kb];
    loadA(an, (const uint4*)Xb, mr, quad);    // prefetch section-2 A
    __syncthreads();
    mfmaSec(a, Bs, acc, lane);                // section 1

    __syncthreads();
    stageB((const uint4*)BtX, Bs, tid);
#pragma unroll
    for (int kb = 0; kb < 4; kb++) a[kb] = scale8(an[kb], lamx);   // fold per-row gate into A
    __syncthreads();
    mfmaSec(a, Bs, acc, lane);                // section 2

    // epilogue: relu + 128->10 projection (lin_w from LDS), shuffle-reduce over l16
    int rbase = tile + wave * 16 + quad * 4;
    float part[4][10];
#pragma unroll
    for (int rr = 0; rr < 4; rr++)
#pragma unroll
        for (int c = 0; c < 10; c++) part[rr][c] = 0.f;

#pragma unroll
    for (int nt = 0; nt < 8; nt++) {
        const float* lw = lws + (nt * 16 + l16) * 10;
        float lwv[10];
#pragma unroll
        for (int c = 0; c < 10; c++) lwv[c] = lw[c];
#pragma unroll
        for (int rr = 0; rr < 4; rr++) {
            float p = acc[nt][rr];
            p = p > 0.f ? p : 0.f;
#pragma unroll
            for (int c = 0; c < 10; c++) part[rr][c] += p * lwv[c];
        }
    }
#pragma unroll
    for (int rr = 0; rr < 4; rr++)
#pragma unroll
        for (int c = 0; c < 10; c++) {
            part[rr][c] += __shfl_xor(part[rr][c], 1);
            part[rr][c] += __shfl_xor(part[rr][c], 2);
            part[rr][c] += __shfl_xor(part[rr][c], 4);
            part[rr][c] += __shfl_xor(part[rr][c], 8);
        }
    if (l16 == 0) {
#pragma unroll
        for (int rr = 0; rr < 4; rr++) {
            int row = rbase + rr;
            if (row < M) {
#pragma unroll
                for (int c = 0; c < 10; c++)
                    out[(size_t)row * 10 + c] = part[rr][c] + lin_b[c];
            }
        }
    }
}

// ---------------- launch ----------------

extern "C" void kernel_launch(void* const* d_in, const int* in_sizes, int n_in,
                              void* d_out, int out_size, void* d_ws, size_t ws_size,
                              hipStream_t stream) {
    const float* x = (const float*)d_in[0];
    const int* ei = (const int*)d_in[1];
    const float* mask = (const float*)d_in[2];
    const float* W1L = (const float*)d_in[3];
    const float* W1H = (const float*)d_in[4];
    const float* W2L = (const float*)d_in[5];
    const float* W2H = (const float*)d_in[6];
    const float* WX = (const float*)d_in[7];
    const float* lam1 = (const float*)d_in[8];
    const float* lam2 = (const float*)d_in[9];
    const float* lin_w = (const float*)d_in[10];
    const float* lin_b = (const float*)d_in[11];
    float* out = (float*)d_out;

    int E = in_sizes[1] / 2;
    int n = in_sizes[2];

    char* w = (char*)d_ws;
    size_t off = 0;
    auto alloc = [&](size_t bytes) -> void* {
        off = (off + 255) & ~(size_t)255;
        void* p = w + off;
        off += bytes;
        return p;
    };
    u32* cntP = (u32*)alloc((size_t)n * 4);
    u64* bits = (u64*)alloc((size_t)((n + 63) / 64 + 1) * 8);
    int* rowptr = (int*)alloc((size_t)(n + 1) * 4);
    int* cursL = (int*)alloc((size_t)n * 4);
    int* cursH = (int*)alloc((size_t)n * 4);
    int* midp = (int*)alloc((size_t)n * 4);
    int* blocksum = (int*)alloc(128 * 4);
    int* sorted = (int*)alloc((size_t)E * 4);
    float* dinvL = (float*)alloc((size_t)n * 4);
    float* dinvH = (float*)alloc((size_t)n * 4);
    float* dinvLL = (float*)alloc((size_t)n * 4);
    float* dinvHH = (float*)alloc((size_t)n * 4);
    float2* diag1 = (float2*)alloc((size_t)n * 8);
    float2* diag2 = (float2*)alloc((size_t)n * 8);
    u16* Bt = (u16*)alloc(5 * 16384 * 2);
    size_t actb = (size_t)n * 128 * 2;
    u16* Xb = (u16*)alloc(actb);
    u16* B0 = (u16*)alloc(actb);
    u16* B1 = (u16*)alloc(actb);
    u16* B2 = (u16*)alloc(actb);
    u16* B3 = (u16*)alloc(actb);

    hipMemsetAsync(cntP, 0, (size_t)n * 4, stream);

    int eblk = (E + 255) / 256;
    int nblkScan = (n + SCAN_B - 1) / SCAN_B;

    int total4 = n * 128 / 4;
    int cvtBlocks = (total4 + 255) / 256;
    int maskBlocks = ((n + 63) / 64 + 3) / 4;   // 4 waves/block, 64 mask bits per wave

    pre_k<<<cvtBlocks + maskBlocks, 256, 0, stream>>>(x, Xb, total4, cvtBlocks, mask, bits, n);
    edge_stats<<<eblk, 256, 0, stream>>>(ei, bits, cntP, E);
    scanA<<<nblkScan, 1024, 0, stream>>>(cntP, rowptr, blocksum, n);
    scanBC<<<nblkScan, 256, 0, stream>>>(blocksum, nblkScan, rowptr, cntP, mask,
                                         cursL, cursH, midp,
                                         dinvL, dinvH, dinvLL, dinvHH, diag1, diag2, n);
    scatter_edges<<<eblk, 256, 0, stream>>>(ei, bits, cursL, cursH, sorted, E);

    int rowsblk = (n + 3) / 4;
    int gemmblk = (n + 63) / 64;

    // layer 1: dual spmm from x, then two GEMMs with relu (LDS-staged, 2 jobs)
    spmm1<<<rowsblk, 256, 0, stream>>>(Xb, rowptr, sorted, mask, dinvL, dinvH, diag1, B0, B1, n);
    transposeW<<<320, 256, 0, stream>>>(W1L, W1H, W2L, W2H, WX, lam1, lam2, Bt);
    gemm_lds<<<dim3(gemmblk, 2), 256, 0, stream>>>(B0, Bt + 0 * 16384, B2,
                                                   B1, Bt + 1 * 16384, B3, n);

    // layer 2: dual spmm (partitioned)
    spmm2<<<rowsblk, 256, 0, stream>>>(B2, B3, rowptr, midp, sorted, dinvLL, dinvHH, diag2, B0, B1, n);

    // fused: relu(Zl@(laml*W2L) + Zh@(lamh*W2H) + lamx*Xb@WX) @ lin_w + b
    fused_final<<<gemmblk, 256, 0, stream>>>(B0, B1, Xb,
                                             Bt + 2 * 16384, Bt + 3 * 16384, Bt + 4 * 16384,
                                             mask, lam1, lam2, lin_w, lin_b, out, n);
}

// Round 7
// 522.726 us; speedup vs baseline: 1.0227x; 1.0227x over previous
//
#include <hip/hip_runtime.h>
#include <stdint.h>

typedef unsigned int u32;
typedef unsigned short u16;
typedef unsigned long long u64;

#define DI __device__ __forceinline__

DI float bf2f(u16 u) { union { u32 i; float f; } v; v.i = ((u32)u) << 16; return v.f; }
DI u16 f2bf(float f) {
    union { u32 i; float f; } v; v.f = f;
    u32 u = v.i;
    u32 r = (u + 0x7fffu + ((u >> 16) & 1u)) >> 16;
    return (u16)r;
}
DI float2 unpack2(u32 x) { return make_float2(bf2f((u16)(x & 0xffffu)), bf2f((u16)(x >> 16))); }
DI u32 pack2(float a, float b) { return (u32)f2bf(a) | ((u32)f2bf(b) << 16); }

DI void fma8(float* acc, float w, uint4 xv) {
    float2 f0 = unpack2(xv.x), f1 = unpack2(xv.y), f2 = unpack2(xv.z), f3 = unpack2(xv.w);
    acc[0] += w * f0.x; acc[1] += w * f0.y; acc[2] += w * f1.x; acc[3] += w * f1.y;
    acc[4] += w * f2.x; acc[5] += w * f2.y; acc[6] += w * f3.x; acc[7] += w * f3.y;
}

DI uint4 scale8(uint4 v, float s) {
    uint4 r;
    float2 f;
    f = unpack2(v.x); r.x = pack2(f.x * s, f.y * s);
    f = unpack2(v.y); r.y = pack2(f.x * s, f.y * s);
    f = unpack2(v.z); r.z = pack2(f.x * s, f.y * s);
    f = unpack2(v.w); r.w = pack2(f.x * s, f.y * s);
    return r;
}

// ---------------- pre: x->bf16 convert + mask bit array (fused) ----------------

__global__ void pre_k(const float* __restrict__ X, u16* __restrict__ Xb, int total4, int cvtBlocks,
                      const float* __restrict__ mask, u64* __restrict__ bits, int n) {
    if ((int)blockIdx.x < cvtBlocks) {
        int i = blockIdx.x * blockDim.x + threadIdx.x;
        if (i >= total4) return;
        float4 v = ((const float4*)X)[i];
        ushort4 o;
        o.x = f2bf(v.x); o.y = f2bf(v.y); o.z = f2bf(v.z); o.w = f2bf(v.w);
        ((ushort4*)Xb)[i] = o;
    } else {
        int bid = blockIdx.x - cvtBlocks;
        int i = bid * 256 + threadIdx.x;
        bool m = (i < n) && (mask[i] != 0.f);
        u64 word = __ballot(m);
        if ((threadIdx.x & 63) == 0) {
            if (i < n) bits[i >> 6] = word;
        }
    }
}

// ---------------- radix-style CSR build (no scattered global writes/atomics) ----------------
// bucket = row >> 7 (128 rows/bucket); NB buckets <= 800; chunk = 8192 edges/block

#define CHUNK 8192
#define NBPAD 800

__global__ __launch_bounds__(256) void k_count(const int* __restrict__ ei, int E, int NB,
                                               u32* __restrict__ hist2d) {
    __shared__ u32 hist[NBPAD];
    for (int i = threadIdx.x; i < NBPAD; i += 256) hist[i] = 0;
    __syncthreads();
    int base = blockIdx.x * CHUNK;
    int end = min(base + CHUNK, E);
    for (int e = base + threadIdx.x; e < end; e += 256) {
        int c = ei[e], r = ei[E + e];
        if (r != c) atomicAdd(&hist[r >> 7], 1u);
    }
    __syncthreads();
    u32* out = hist2d + (size_t)blockIdx.x * NBPAD;
    for (int i = threadIdx.x; i < NB; i += 256) out[i] = hist[i];
}

__global__ __launch_bounds__(1024) void k_bucketscan(const u32* __restrict__ hist2d,
                                                     u32* __restrict__ off2d,
                                                     int NBLK, int NB, u32* __restrict__ bbase) {
    __shared__ u32 s[1024];
    int t = threadIdx.x;
    u32 total = 0;
    if (t < NB) {
        for (int k = 0; k < NBLK; k++) {
            u32 v = hist2d[(size_t)k * NBPAD + t];
            off2d[(size_t)k * NBPAD + t] = total;
            total += v;
        }
    }
    s[t] = (t < NB) ? total : 0;
    __syncthreads();
    for (int off = 1; off < 1024; off <<= 1) {
        u32 tmp = (t >= off) ? s[t - off] : 0;
        __syncthreads();
        s[t] += tmp;
        __syncthreads();
    }
    u32 base = (t == 0) ? 0u : s[t - 1];
    if (t < NB) {
        bbase[t] = base;
        for (int k = 0; k < NBLK; k++) off2d[(size_t)k * NBPAD + t] += base;
    }
    if (t == 0) bbase[NB] = s[1023];
}

// entry = row_low(7) | col<<7 (17) | maskbit<<31
__global__ __launch_bounds__(256) void k_scatter(const int* __restrict__ ei, int E, int NB,
                                                 const u32* __restrict__ off2d,
                                                 const u64* __restrict__ bits,
                                                 u32* __restrict__ bentry) {
    __shared__ u32 cur[NBPAD];
    const u32* off = off2d + (size_t)blockIdx.x * NBPAD;
    for (int i = threadIdx.x; i < NB; i += 256) cur[i] = off[i];
    __syncthreads();
    int base = blockIdx.x * CHUNK;
    int end = min(base + CHUNK, E);
    for (int e = base + threadIdx.x; e < end; e += 256) {
        int c = ei[e], r = ei[E + e];
        if (r != c) {
            u32 pos = atomicAdd(&cur[r >> 7], 1u);
            u32 m = (u32)((bits[c >> 6] >> (c & 63)) & 1);
            bentry[pos] = (u32)(r & 127) | ((u32)c << 7) | (m << 31);
        }
    }
}

// per-bucket dense row histogram -> cntP (lo16=cnt, hi16=cntm). replaces edge_stats.
__global__ __launch_bounds__(256) void k_rowhist(const u32* __restrict__ bentry,
                                                 const u32* __restrict__ bbase,
                                                 u32* __restrict__ cntP, int n) {
    __shared__ u32 h[128];
    if (threadIdx.x < 128) h[threadIdx.x] = 0;
    __syncthreads();
    u32 s0 = bbase[blockIdx.x], s1 = bbase[blockIdx.x + 1];
    for (u32 i = s0 + threadIdx.x; i < s1; i += 256) {
        u32 e = bentry[i];
        atomicAdd(&h[e & 127], 1u + ((e >> 31) << 16));
    }
    __syncthreads();
    int row = blockIdx.x * 128 + threadIdx.x;
    if (threadIdx.x < 128 && row < n) cntP[row] = h[threadIdx.x];
}

#define SCAN_B 1024
__global__ __launch_bounds__(1024) void scanA(const u32* __restrict__ cntP, int* __restrict__ rowptr,
                                              int* __restrict__ blocksum, int n) {
    __shared__ int s[SCAN_B];
    int t = threadIdx.x;
    int i = blockIdx.x * SCAN_B + t;
    int v = (i < n) ? (int)(cntP[i] & 0xffffu) : 0;
    s[t] = v; __syncthreads();
    for (int off = 1; off < SCAN_B; off <<= 1) {
        int tmp = (t >= off) ? s[t - off] : 0;
        __syncthreads();
        s[t] += tmp;
        __syncthreads();
    }
    if (i < n) rowptr[i] = s[t] - v;
    if (t == SCAN_B - 1) blocksum[blockIdx.x] = s[t];
}

__global__ __launch_bounds__(256) void scanBC(const int* __restrict__ blocksum, int nblk,
                                              int* __restrict__ rowptr, const u32* __restrict__ cntP,
                                              const float* __restrict__ mask,
                                              int* __restrict__ mid,
                                              float* __restrict__ dinvL, float* __restrict__ dinvH,
                                              float* __restrict__ dinvLL, float* __restrict__ dinvHH,
                                              float2* __restrict__ diag1, float2* __restrict__ diag2, int n) {
    __shared__ int s[128];
    int t = threadIdx.x;
    if (t < 128) s[t] = (t < nblk) ? blocksum[t] : 0;
    __syncthreads();
    for (int off = 1; off < 128; off <<= 1) {
        int tmp = (t >= off && t < 128) ? s[t - off] : 0;
        __syncthreads();
        if (t < 128) s[t] += tmp;
        __syncthreads();
    }
    int blockoff = (blockIdx.x == 0) ? 0 : s[blockIdx.x - 1];
    if (blockIdx.x == 0 && t == 0) rowptr[n] = s[127];
#pragma unroll
    for (int k = 0; k < 4; k++) {
        int i = blockIdx.x * SCAN_B + k * 256 + t;
        if (i >= n) break;
        int v = rowptr[i] + blockoff;
        rowptr[i] = v;
        u32 p = cntP[i];
        int ci = (int)(p & 0xffffu);
        int cmi = (int)(p >> 16);
        mid[i] = v + cmi;
        float c = (float)ci;
        float cm = (float)cmi;
        bool mi = mask[i] != 0.f;
        float degL = (mi ? c : 0.f) + 1.f;
        float degH = (mi ? 0.f : c) + 1.f;
        float degLL = cm + 1.f;
        float degHH = (c - cm) + 1.f;
        dinvL[i] = rsqrtf(degL);
        dinvH[i] = rsqrtf(degH);
        dinvLL[i] = rsqrtf(degLL);
        dinvHH[i] = rsqrtf(degHH);
        diag1[i] = make_float2(1.f / degL, 1.f / degH);
        diag2[i] = make_float2(1.f / degLL, 1.f / degHH);
    }
}

// per-bucket CSR placement into the bucket's contiguous span of `sorted`
__global__ __launch_bounds__(256) void k_place(const u32* __restrict__ bentry,
                                               const u32* __restrict__ bbase,
                                               const int* __restrict__ rowptr, const int* __restrict__ mid,
                                               int* __restrict__ sorted, int n) {
    __shared__ int cur[256];
    int row = blockIdx.x * 128 + threadIdx.x;
    if (threadIdx.x < 128) {
        int rr = min(row, n - 1);
        cur[threadIdx.x] = rowptr[rr];       // L cursor (masked sources, front)
        cur[128 + threadIdx.x] = mid[rr];    // H cursor (unmasked, back)
    }
    __syncthreads();
    u32 s0 = bbase[blockIdx.x], s1 = bbase[blockIdx.x + 1];
    for (u32 i = s0 + threadIdx.x; i < s1; i += 256) {
        u32 e = bentry[i];
        int rl = e & 127;
        int col = (int)((e >> 7) & 0x1FFFF);
        int isH = (int)((e >> 31) ^ 1u);
        int pos = atomicAdd(&cur[rl + (isH << 7)], 1);
        sorted[pos] = col;
    }
}

// ---------------- SpMM layer 1 ----------------

__global__ __launch_bounds__(256) void spmm1(const u16* __restrict__ X,
                                             const int* __restrict__ rowptr, const int* __restrict__ sorted,
                                             const float* __restrict__ mask,
                                             const float* __restrict__ dinvL, const float* __restrict__ dinvH,
                                             const float2* __restrict__ diag1,
                                             u16* __restrict__ Yl, u16* __restrict__ Yh, int n) {
    int r = blockIdx.x * 4 + (threadIdx.x >> 6);
    if (r >= n) return;
    int lane = threadIdx.x & 63;
    int q = lane >> 4, l16 = lane & 15;
    bool mi = mask[r] != 0.f;
    const float* dinvA = mi ? dinvL : dinvH;
    float da = dinvA[r];
    float2 dg = diag1[r];
    float diag = mi ? dg.x : dg.y;

    const uint4* Xv = (const uint4*)X;
    uint4 xown = Xv[(size_t)r * 16 + l16];

    float acc[8] = {0.f, 0.f, 0.f, 0.f, 0.f, 0.f, 0.f, 0.f};
    int e0 = rowptr[r], e1 = rowptr[r + 1];
    int last = e1 - 1;
    for (int base = e0; base < e1; base += 8) {
        int s0 = base + q, s1 = base + 4 + q;
        int i0 = min(s0, last), i1 = min(s1, last);
        int c0 = sorted[i0], c1 = sorted[i1];
        float w0 = (s0 < e1) ? da * dinvA[c0] : 0.f;
        float w1 = (s1 < e1) ? da * dinvA[c1] : 0.f;
        uint4 x0 = Xv[(size_t)c0 * 16 + l16];
        uint4 x1 = Xv[(size_t)c1 * 16 + l16];
        fma8(acc, w0, x0);
        fma8(acc, w1, x1);
    }
#pragma unroll
    for (int k = 0; k < 8; k++) {
        acc[k] += __shfl_xor(acc[k], 16);
        acc[k] += __shfl_xor(acc[k], 32);
    }
    float2 o0 = unpack2(xown.x), o1 = unpack2(xown.y), o2 = unpack2(xown.z), o3 = unpack2(xown.w);
    uint4 res;
    res.x = pack2(acc[0] + diag * o0.x, acc[1] + diag * o0.y);
    res.y = pack2(acc[2] + diag * o1.x, acc[3] + diag * o1.y);
    res.z = pack2(acc[4] + diag * o2.x, acc[5] + diag * o2.y);
    res.w = pack2(acc[6] + diag * o3.x, acc[7] + diag * o3.y);
    uint4* Ya = (uint4*)(mi ? Yl : Yh);
    uint4* Yc = (uint4*)(mi ? Yh : Yl);
    if (q == 0) Ya[(size_t)r * 16 + l16] = res;
    if (q == 1) Yc[(size_t)r * 16 + l16] = xown;   // deg=1, diag=1 -> exact copy
}

// ---------------- SpMM layer 2: partitioned rows, two uniform phases ----------------

__global__ __launch_bounds__(256) void spmm2(const u16* __restrict__ XL, const u16* __restrict__ XH,
                                             const int* __restrict__ rowptr, const int* __restrict__ mid,
                                             const int* __restrict__ sorted,
                                             const float* __restrict__ dinvLL, const float* __restrict__ dinvHH,
                                             const float2* __restrict__ diag2,
                                             u16* __restrict__ Zl, u16* __restrict__ Zh, int n) {
    int r = blockIdx.x * 4 + (threadIdx.x >> 6);
    if (r >= n) return;
    int lane = threadIdx.x & 63;
    int q = lane >> 4, l16 = lane & 15;

    float dllr = dinvLL[r], dhhr = dinvHH[r];
    float2 dg = diag2[r];

    const uint4* XLv = (const uint4*)XL;
    const uint4* XHv = (const uint4*)XH;
    uint4 xlown = XLv[(size_t)r * 16 + l16];
    uint4 xhown = XHv[(size_t)r * 16 + l16];

    float accL[8] = {0.f, 0.f, 0.f, 0.f, 0.f, 0.f, 0.f, 0.f};
    float accH[8] = {0.f, 0.f, 0.f, 0.f, 0.f, 0.f, 0.f, 0.f};
    int e0 = rowptr[r], m = mid[r], e1 = rowptr[r + 1];

    int lastL = m - 1;
    for (int base = e0; base < m; base += 8) {
        int s0 = base + q, s1 = base + 4 + q;
        int i0 = min(s0, lastL), i1 = min(s1, lastL);
        int c0 = sorted[i0], c1 = sorted[i1];
        float w0 = (s0 < m) ? dllr * dinvLL[c0] : 0.f;
        float w1 = (s1 < m) ? dllr * dinvLL[c1] : 0.f;
        uint4 x0 = XLv[(size_t)c0 * 16 + l16];
        uint4 x1 = XLv[(size_t)c1 * 16 + l16];
        fma8(accL, w0, x0);
        fma8(accL, w1, x1);
    }
    int lastH = e1 - 1;
    for (int base = m; base < e1; base += 8) {
        int s0 = base + q, s1 = base + 4 + q;
        int i0 = min(s0, lastH), i1 = min(s1, lastH);
        int c0 = sorted[i0], c1 = sorted[i1];
        float w0 = (s0 < e1) ? dhhr * dinvHH[c0] : 0.f;
        float w1 = (s1 < e1) ? dhhr * dinvHH[c1] : 0.f;
        uint4 x0 = XHv[(size_t)c0 * 16 + l16];
        uint4 x1 = XHv[(size_t)c1 * 16 + l16];
        fma8(accH, w0, x0);
        fma8(accH, w1, x1);
    }
#pragma unroll
    for (int k = 0; k < 8; k++) {
        accL[k] += __shfl_xor(accL[k], 16);
        accL[k] += __shfl_xor(accL[k], 32);
        accH[k] += __shfl_xor(accH[k], 16);
        accH[k] += __shfl_xor(accH[k], 32);
    }
    float2 l0 = unpack2(xlown.x), l1 = unpack2(xlown.y), l2 = unpack2(xlown.z), l3 = unpack2(xlown.w);
    float2 h0 = unpack2(xhown.x), h1 = unpack2(xhown.y), h2 = unpack2(xhown.z), h3 = unpack2(xhown.w);
    float cl = dg.x, ch = dg.y;
    uint4 rl, rh;
    rl.x = pack2(accL[0] + cl * l0.x, accL[1] + cl * l0.y);
    rl.y = pack2(accL[2] + cl * l1.x, accL[3] + cl * l1.y);
    rl.z = pack2(accL[4] + cl * l2.x, accL[5] + cl * l2.y);
    rl.w = pack2(accL[6] + cl * l3.x, accL[7] + cl * l3.y);
    rh.x = pack2(accH[0] + ch * h0.x, accH[1] + ch * h0.y);
    rh.y = pack2(accH[2] + ch * h1.x, accH[3] + ch * h1.y);
    rh.z = pack2(accH[4] + ch * h2.x, accH[5] + ch * h2.y);
    rh.w = pack2(accH[6] + ch * h3.x, accH[7] + ch * h3.y);
    if (q == 0) ((uint4*)Zl)[(size_t)r * 16 + l16] = rl;
    if (q == 1) ((uint4*)Zh)[(size_t)r * 16 + l16] = rh;
}

// ---------------- weight transpose f32 -> bf16, lam folded into W2L/W2H ----------------

__global__ void transposeW(const float* __restrict__ W1L, const float* __restrict__ W1H,
                           const float* __restrict__ W2L, const float* __restrict__ W2H,
                           const float* __restrict__ WX,
                           const float* __restrict__ lam1, const float* __restrict__ lam2,
                           u16* __restrict__ Bt) {
    int w = blockIdx.x >> 6;
    int idx = (blockIdx.x & 63) * 256 + threadIdx.x;
    float scale = 1.f;
    if (w == 2) { float e0 = __expf(lam1[0]), e1 = __expf(lam1[1]); scale = e1 / (e0 + e1); }
    if (w == 3) { float f0 = __expf(lam2[0]), f1 = __expf(lam2[1]); scale = f1 / (f0 + f1); }
    const float* src = (w == 0) ? W1L : (w == 1) ? W1H : (w == 2) ? W2L : (w == 3) ? W2H : WX;
    int k = idx >> 7, nn = idx & 127;
    Bt[(size_t)w * 16384 + (size_t)nn * 128 + k] = f2bf(scale * src[idx]);
}

// ---------------- LDS-staged MFMA GEMM building blocks ----------------

typedef __attribute__((ext_vector_type(8))) short bf16x8;
typedef __attribute__((ext_vector_type(4))) float f32x4;

DI void stageB(const uint4* __restrict__ Bt4, uint4* Bs, int tid) {
#pragma unroll
    for (int i = 0; i < 8; i++) {
        int g = i * 256 + tid;
        int nn = g >> 4, c = g & 15;
        int d = ((nn >> 4) * 4 + (c >> 2)) * 64 + (c & 3) * 16 + (nn & 15);
        Bs[d] = Bt4[g];
    }
}

DI void loadA(uint4* a, const uint4* __restrict__ A4, int mr, int quad) {
#pragma unroll
    for (int kb = 0; kb < 4; kb++)
        a[kb] = A4[(size_t)mr * 16 + kb * 4 + quad];
}

DI void mfmaSec(const uint4* a, const uint4* Bs, f32x4* acc, int lane) {
#pragma unroll
    for (int nt = 0; nt < 8; nt++)
#pragma unroll
        for (int kb = 0; kb < 4; kb++) {
            bf16x8 av = *(const bf16x8*)&a[kb];
            bf16x8 bv = *(const bf16x8*)&Bs[(nt * 4 + kb) * 64 + lane];
            acc[nt] = __builtin_amdgcn_mfma_f32_16x16x32_bf16(av, bv, acc[nt], 0, 0, 0);
        }
}

// ---------------- layer-1 GEMM (2 jobs via blockIdx.y), relu, coalesced store ----------------

__global__ __launch_bounds__(256) void gemm_lds(const u16* __restrict__ A0, const u16* __restrict__ Bt0,
                                                u16* __restrict__ C0,
                                                const u16* __restrict__ A1, const u16* __restrict__ Bt1,
                                                u16* __restrict__ C1, int M) {
    __shared__ uint4 Bs[2048];
    const u16* A = blockIdx.y ? A1 : A0;
    const u16* Bt = blockIdx.y ? Bt1 : Bt0;
    u16* C = blockIdx.y ? C1 : C0;

    int tid = threadIdx.x;
    int wave = tid >> 6, lane = tid & 63, quad = lane >> 4, l16 = lane & 15;
    int tile = blockIdx.x * 64;
    int m0 = tile + wave * 16 + l16;
    int mr = min(m0, M - 1);

    uint4 a[4];
    loadA(a, (const uint4*)A, mr, quad);
    stageB((const uint4*)Bt, Bs, tid);
    __syncthreads();

    f32x4 acc[8];
#pragma unroll
    for (int nt = 0; nt < 8; nt++) acc[nt] = f32x4{0.f, 0.f, 0.f, 0.f};
    mfmaSec(a, Bs, acc, lane);

    __syncthreads();
    u16* Cs = (u16*)Bs;
    int lrow0 = wave * 16 + quad * 4;
#pragma unroll
    for (int nt = 0; nt < 8; nt++)
#pragma unroll
        for (int rr = 0; rr < 4; rr++) {
            float v = acc[nt][rr];
            v = v > 0.f ? v : 0.f;
            Cs[(lrow0 + rr) * 128 + nt * 16 + l16] = f2bf(v);
        }
    __syncthreads();
    uint4* Cs4 = (uint4*)Bs;
    uint4* C4 = (uint4*)C;
#pragma unroll
    for (int i = 0; i < 4; i++) {
        int g = i * 256 + tid;
        int grow = tile + (g >> 4);
        if (grow < M) C4[(size_t)grow * 16 + (g & 15)] = Cs4[g];
    }
}

// ---------------- fused final ----------------

__global__ __launch_bounds__(256) void fused_final(const u16* __restrict__ Zl, const u16* __restrict__ Zh,
                                                   const u16* __restrict__ Xb,
                                                   const u16* __restrict__ BtL, const u16* __restrict__ BtH,
                                                   const u16* __restrict__ BtX,
                                                   const float* __restrict__ mask,
                                                   const float* __restrict__ lam1, const float* __restrict__ lam2,
                                                   const float* __restrict__ lin_w, const float* __restrict__ lin_b,
                                                   float* __restrict__ out, int M) {
    __shared__ uint4 Bs[2048];
    __shared__ float lws[1280];

    int tid = threadIdx.x;
    int wave = tid >> 6, lane = tid & 63, quad = lane >> 4, l16 = lane & 15;
    int tile = blockIdx.x * 64;
    int m0 = tile + wave * 16 + l16;
    int mr = min(m0, M - 1);

    uint4 a[4], an[4];
    loadA(a, (const uint4*)Zl, mr, quad);
    {
        const uint4* lw4 = (const uint4*)lin_w;
        uint4* lws4 = (uint4*)lws;
        lws4[tid] = lw4[tid];
        if (tid < 64) lws4[256 + tid] = lw4[256 + tid];
    }
    stageB((const uint4*)BtL, Bs, tid);

    float e0 = __expf(lam1[0]), e1 = __expf(lam1[1]);
    float lamxl = e0 / (e0 + e1);
    float f0 = __expf(lam2[0]), f1 = __expf(lam2[1]);
    float lamxh = f0 / (f0 + f1);
    float lamx = (mask[mr] != 0.f) ? lamxl : lamxh;

    __syncthreads();

    f32x4 acc[8];
#pragma unroll
    for (int nt = 0; nt < 8; nt++) acc[nt] = f32x4{0.f, 0.f, 0.f, 0.f};

    loadA(an, (const uint4*)Zh, mr, quad);
    mfmaSec(a, Bs, acc, lane);

    __syncthreads();
    stageB((const uint4*)BtH, Bs, tid);
#pragma unroll
    for (int kb = 0; kb < 4; kb++) a[kb] = an[kb];
    loadA(an, (const uint4*)Xb, mr, quad);
    __syncthreads();
    mfmaSec(a, Bs, acc, lane);

    __syncthreads();
    stageB((const uint4*)BtX, Bs, tid);
#pragma unroll
    for (int kb = 0; kb < 4; kb++) a[kb] = scale8(an[kb], lamx);
    __syncthreads();
    mfmaSec(a, Bs, acc, lane);

    int rbase = tile + wave * 16 + quad * 4;
    float part[4][10];
#pragma unroll
    for (int rr = 0; rr < 4; rr++)
#pragma unroll
        for (int c = 0; c < 10; c++) part[rr][c] = 0.f;

#pragma unroll
    for (int nt = 0; nt < 8; nt++) {
        const float* lw = lws + (nt * 16 + l16) * 10;
        float lwv[10];
#pragma unroll
        for (int c = 0; c < 10; c++) lwv[c] = lw[c];
#pragma unroll
        for (int rr = 0; rr < 4; rr++) {
            float p = acc[nt][rr];
            p = p > 0.f ? p : 0.f;
#pragma unroll
            for (int c = 0; c < 10; c++) part[rr][c] += p * lwv[c];
        }
    }
#pragma unroll
    for (int rr = 0; rr < 4; rr++)
#pragma unroll
        for (int c = 0; c < 10; c++) {
            part[rr][c] += __shfl_xor(part[rr][c], 1);
            part[rr][c] += __shfl_xor(part[rr][c], 2);
            part[rr][c] += __shfl_xor(part[rr][c], 4);
            part[rr][c] += __shfl_xor(part[rr][c], 8);
        }
    if (l16 == 0) {
#pragma unroll
        for (int rr = 0; rr < 4; rr++) {
            int row = rbase + rr;
            if (row < M) {
#pragma unroll
                for (int c = 0; c < 10; c++)
                    out[(size_t)row * 10 + c] = part[rr][c] + lin_b[c];
            }
        }
    }
}

// ---------------- launch ----------------

extern "C" void kernel_launch(void* const* d_in, const int* in_sizes, int n_in,
                              void* d_out, int out_size, void* d_ws, size_t ws_size,
                              hipStream_t stream) {
    const float* x = (const float*)d_in[0];
    const int* ei = (const int*)d_in[1];
    const float* mask = (const float*)d_in[2];
    const float* W1L = (const float*)d_in[3];
    const float* W1H = (const float*)d_in[4];
    const float* W2L = (const float*)d_in[5];
    const float* W2H = (const float*)d_in[6];
    const float* WX = (const float*)d_in[7];
    const float* lam1 = (const float*)d_in[8];
    const float* lam2 = (const float*)d_in[9];
    const float* lin_w = (const float*)d_in[10];
    const float* lin_b = (const float*)d_in[11];
    float* out = (float*)d_out;

    int E = in_sizes[1] / 2;
    int n = in_sizes[2];
    int NB = (n + 127) >> 7;                   // 782 for n=100000 (<= NBPAD)
    int NBLK = (E + CHUNK - 1) / CHUNK;        // 196 for E=1.6M

    char* w = (char*)d_ws;
    size_t off = 0;
    auto alloc = [&](size_t bytes) -> void* {
        off = (off + 255) & ~(size_t)255;
        void* p = w + off;
        off += bytes;
        return p;
    };
    u32* cntP = (u32*)alloc((size_t)n * 4);
    u64* bits = (u64*)alloc((size_t)((n + 63) / 64 + 1) * 8);
    int* rowptr = (int*)alloc((size_t)(n + 1) * 4);
    int* midp = (int*)alloc((size_t)n * 4);
    int* blocksum = (int*)alloc(128 * 4);
    u32* hist2d = (u32*)alloc((size_t)NBLK * NBPAD * 4);
    u32* off2d = (u32*)alloc((size_t)NBLK * NBPAD * 4);
    u32* bbase = (u32*)alloc((size_t)(NB + 1) * 4);
    u32* bentry = (u32*)alloc((size_t)E * 4);
    int* sorted = (int*)alloc((size_t)E * 4);
    float* dinvL = (float*)alloc((size_t)n * 4);
    float* dinvH = (float*)alloc((size_t)n * 4);
    float* dinvLL = (float*)alloc((size_t)n * 4);
    float* dinvHH = (float*)alloc((size_t)n * 4);
    float2* diag1 = (float2*)alloc((size_t)n * 8);
    float2* diag2 = (float2*)alloc((size_t)n * 8);
    u16* Bt = (u16*)alloc(5 * 16384 * 2);
    size_t actb = (size_t)n * 128 * 2;
    u16* Xb = (u16*)alloc(actb);
    u16* B0 = (u16*)alloc(actb);
    u16* B1 = (u16*)alloc(actb);
    u16* B2 = (u16*)alloc(actb);
    u16* B3 = (u16*)alloc(actb);

    int nblkScan = (n + SCAN_B - 1) / SCAN_B;
    int total4 = n * 128 / 4;
    int cvtBlocks = (total4 + 255) / 256;
    int maskBlocks = ((n + 63) / 64 + 3) / 4;

    pre_k<<<cvtBlocks + maskBlocks, 256, 0, stream>>>(x, Xb, total4, cvtBlocks, mask, bits, n);
    k_count<<<NBLK, 256, 0, stream>>>(ei, E, NB, hist2d);
    k_bucketscan<<<1, 1024, 0, stream>>>(hist2d, off2d, NBLK, NB, bbase);
    k_scatter<<<NBLK, 256, 0, stream>>>(ei, E, NB, off2d, bits, bentry);
    k_rowhist<<<NB, 256, 0, stream>>>(bentry, bbase, cntP, n);
    scanA<<<nblkScan, 1024, 0, stream>>>(cntP, rowptr, blocksum, n);
    scanBC<<<nblkScan, 256, 0, stream>>>(blocksum, nblkScan, rowptr, cntP, mask, midp,
                                         dinvL, dinvH, dinvLL, dinvHH, diag1, diag2, n);
    k_place<<<NB, 256, 0, stream>>>(bentry, bbase, rowptr, midp, sorted, n);

    int rowsblk = (n + 3) / 4;
    int gemmblk = (n + 63) / 64;

    spmm1<<<rowsblk, 256, 0, stream>>>(Xb, rowptr, sorted, mask, dinvL, dinvH, diag1, B0, B1, n);
    transposeW<<<320, 256, 0, stream>>>(W1L, W1H, W2L, W2H, WX, lam1, lam2, Bt);
    gemm_lds<<<dim3(gemmblk, 2), 256, 0, stream>>>(B0, Bt + 0 * 16384, B2,
                                                   B1, Bt + 1 * 16384, B3, n);

    spmm2<<<rowsblk, 256, 0, stream>>>(B2, B3, rowptr, midp, sorted, dinvLL, dinvHH, diag2, B0, B1, n);

    fused_final<<<gemmblk, 256, 0, stream>>>(B0, B1, Xb,
                                             Bt + 2 * 16384, Bt + 3 * 16384, Bt + 4 * 16384,
                                             mask, lam1, lam2, lin_w, lin_b, out, n);
}

// Round 8
// 413.326 us; speedup vs baseline: 1.2934x; 1.2647x over previous
//
#include <hip/hip_runtime.h>
#include <stdint.h>

typedef unsigned int u32;
typedef unsigned short u16;
typedef unsigned long long u64;

#define DI __device__ __forceinline__

DI float bf2f(u16 u) { union { u32 i; float f; } v; v.i = ((u32)u) << 16; return v.f; }
DI u16 f2bf(float f) {
    union { u32 i; float f; } v; v.f = f;
    u32 u = v.i;
    u32 r = (u + 0x7fffu + ((u >> 16) & 1u)) >> 16;
    return (u16)r;
}
DI float2 unpack2(u32 x) { return make_float2(bf2f((u16)(x & 0xffffu)), bf2f((u16)(x >> 16))); }
DI u32 pack2(float a, float b) { return (u32)f2bf(a) | ((u32)f2bf(b) << 16); }

DI void fma8(float* acc, float w, uint4 xv) {
    float2 f0 = unpack2(xv.x), f1 = unpack2(xv.y), f2 = unpack2(xv.z), f3 = unpack2(xv.w);
    acc[0] += w * f0.x; acc[1] += w * f0.y; acc[2] += w * f1.x; acc[3] += w * f1.y;
    acc[4] += w * f2.x; acc[5] += w * f2.y; acc[6] += w * f3.x; acc[7] += w * f3.y;
}

DI uint4 scale8(uint4 v, float s) {
    uint4 r;
    float2 f;
    f = unpack2(v.x); r.x = pack2(f.x * s, f.y * s);
    f = unpack2(v.y); r.y = pack2(f.x * s, f.y * s);
    f = unpack2(v.z); r.z = pack2(f.x * s, f.y * s);
    f = unpack2(v.w); r.w = pack2(f.x * s, f.y * s);
    return r;
}

// ---------------- pre: x->bf16 convert + mask bit array (fused) ----------------

__global__ void pre_k(const float* __restrict__ X, u16* __restrict__ Xb, int total4, int cvtBlocks,
                      const float* __restrict__ mask, u64* __restrict__ bits, int n) {
    if ((int)blockIdx.x < cvtBlocks) {
        int i = blockIdx.x * blockDim.x + threadIdx.x;
        if (i >= total4) return;
        float4 v = ((const float4*)X)[i];
        ushort4 o;
        o.x = f2bf(v.x); o.y = f2bf(v.y); o.z = f2bf(v.z); o.w = f2bf(v.w);
        ((ushort4*)Xb)[i] = o;
    } else {
        int bid = blockIdx.x - cvtBlocks;
        int i = bid * 256 + threadIdx.x;
        bool m = (i < n) && (mask[i] != 0.f);
        u64 word = __ballot(m);
        if ((threadIdx.x & 63) == 0) {
            if (i < n) bits[i >> 6] = word;
        }
    }
}

// ---------------- radix-style CSR build (no scattered global writes/atomics) ----------------
// bucket = row >> 7 (128 rows/bucket); NB buckets <= 800; chunk = 8192 edges/block

#define CHUNK 8192
#define NBPAD 800

__global__ __launch_bounds__(256) void k_count(const int* __restrict__ ei, int E, int NB,
                                               u32* __restrict__ hist2d) {
    __shared__ u32 hist[NBPAD];
    for (int i = threadIdx.x; i < NBPAD; i += 256) hist[i] = 0;
    __syncthreads();
    int base = blockIdx.x * CHUNK;
    int end = min(base + CHUNK, E);
    for (int e = base + threadIdx.x; e < end; e += 256) {
        int c = ei[e], r = ei[E + e];
        if (r != c) atomicAdd(&hist[r >> 7], 1u);
    }
    __syncthreads();
    u32* out = hist2d + (size_t)blockIdx.x * NBPAD;
    for (int i = threadIdx.x; i < NB; i += 256) out[i] = hist[i];
}

// per-bucket scan over the NBLK chunk-counts (one block per bucket; parallel loads)
__global__ __launch_bounds__(256) void k_colscan(const u32* __restrict__ hist2d,
                                                 u32* __restrict__ off2d,
                                                 int NBLK, u32* __restrict__ btotal) {
    __shared__ u32 s[256];
    int t = blockIdx.x;    // bucket
    int k = threadIdx.x;   // chunk index
    u32 v = (k < NBLK) ? hist2d[(size_t)k * NBPAD + t] : 0;
    s[k] = v;
    __syncthreads();
    for (int off = 1; off < 256; off <<= 1) {
        u32 tmp = (k >= off) ? s[k - off] : 0;
        __syncthreads();
        s[k] += tmp;
        __syncthreads();
    }
    if (k < NBLK) off2d[(size_t)k * NBPAD + t] = s[k] - v;   // local exclusive
    if (k == 0) btotal[t] = s[255];
}

// scan of bucket totals -> bucket bases (tiny)
__global__ __launch_bounds__(1024) void k_basescan(const u32* __restrict__ btotal,
                                                   u32* __restrict__ bbase, int NB) {
    __shared__ u32 s[1024];
    int t = threadIdx.x;
    u32 v = (t < NB) ? btotal[t] : 0;
    s[t] = v;
    __syncthreads();
    for (int off = 1; off < 1024; off <<= 1) {
        u32 tmp = (t >= off) ? s[t - off] : 0;
        __syncthreads();
        s[t] += tmp;
        __syncthreads();
    }
    if (t < NB) bbase[t] = s[t] - v;
    if (t == NB - 1) bbase[NB] = s[t];
}

// entry = row_low(7) | col<<7 (17) | maskbit<<31
__global__ __launch_bounds__(256) void k_scatter(const int* __restrict__ ei, int E, int NB,
                                                 const u32* __restrict__ off2d,
                                                 const u32* __restrict__ bbase,
                                                 const u64* __restrict__ bits,
                                                 u32* __restrict__ bentry) {
    __shared__ u32 cur[NBPAD];
    const u32* off = off2d + (size_t)blockIdx.x * NBPAD;
    for (int i = threadIdx.x; i < NB; i += 256) cur[i] = off[i] + bbase[i];
    __syncthreads();
    int base = blockIdx.x * CHUNK;
    int end = min(base + CHUNK, E);
    for (int e = base + threadIdx.x; e < end; e += 256) {
        int c = ei[e], r = ei[E + e];
        if (r != c) {
            u32 pos = atomicAdd(&cur[r >> 7], 1u);
            u32 m = (u32)((bits[c >> 6] >> (c & 63)) & 1);
            bentry[pos] = (u32)(r & 127) | ((u32)c << 7) | (m << 31);
        }
    }
}

// per-bucket dense row histogram -> cntP (lo16=cnt, hi16=cntm)
__global__ __launch_bounds__(256) void k_rowhist(const u32* __restrict__ bentry,
                                                 const u32* __restrict__ bbase,
                                                 u32* __restrict__ cntP, int n) {
    __shared__ u32 h[128];
    if (threadIdx.x < 128) h[threadIdx.x] = 0;
    __syncthreads();
    u32 s0 = bbase[blockIdx.x], s1 = bbase[blockIdx.x + 1];
    for (u32 i = s0 + threadIdx.x; i < s1; i += 256) {
        u32 e = bentry[i];
        atomicAdd(&h[e & 127], 1u + ((e >> 31) << 16));
    }
    __syncthreads();
    int row = blockIdx.x * 128 + threadIdx.x;
    if (threadIdx.x < 128 && row < n) cntP[row] = h[threadIdx.x];
}

#define SCAN_B 1024
__global__ __launch_bounds__(1024) void scanA(const u32* __restrict__ cntP, int* __restrict__ rowptr,
                                              int* __restrict__ blocksum, int n) {
    __shared__ int s[SCAN_B];
    int t = threadIdx.x;
    int i = blockIdx.x * SCAN_B + t;
    int v = (i < n) ? (int)(cntP[i] & 0xffffu) : 0;
    s[t] = v; __syncthreads();
    for (int off = 1; off < SCAN_B; off <<= 1) {
        int tmp = (t >= off) ? s[t - off] : 0;
        __syncthreads();
        s[t] += tmp;
        __syncthreads();
    }
    if (i < n) rowptr[i] = s[t] - v;
    if (t == SCAN_B - 1) blocksum[blockIdx.x] = s[t];
}

__global__ __launch_bounds__(256) void scanBC(const int* __restrict__ blocksum, int nblk,
                                              int* __restrict__ rowptr, const u32* __restrict__ cntP,
                                              const float* __restrict__ mask,
                                              int* __restrict__ mid,
                                              float* __restrict__ dinvL, float* __restrict__ dinvH,
                                              float* __restrict__ dinvLL, float* __restrict__ dinvHH,
                                              float2* __restrict__ diag1, float2* __restrict__ diag2, int n) {
    __shared__ int s[128];
    int t = threadIdx.x;
    if (t < 128) s[t] = (t < nblk) ? blocksum[t] : 0;
    __syncthreads();
    for (int off = 1; off < 128; off <<= 1) {
        int tmp = (t >= off && t < 128) ? s[t - off] : 0;
        __syncthreads();
        if (t < 128) s[t] += tmp;
        __syncthreads();
    }
    int blockoff = (blockIdx.x == 0) ? 0 : s[blockIdx.x - 1];
    if (blockIdx.x == 0 && t == 0) rowptr[n] = s[127];
#pragma unroll
    for (int k = 0; k < 4; k++) {
        int i = blockIdx.x * SCAN_B + k * 256 + t;
        if (i >= n) break;
        int v = rowptr[i] + blockoff;
        rowptr[i] = v;
        u32 p = cntP[i];
        int ci = (int)(p & 0xffffu);
        int cmi = (int)(p >> 16);
        mid[i] = v + cmi;
        float c = (float)ci;
        float cm = (float)cmi;
        bool mi = mask[i] != 0.f;
        float degL = (mi ? c : 0.f) + 1.f;
        float degH = (mi ? 0.f : c) + 1.f;
        float degLL = cm + 1.f;
        float degHH = (c - cm) + 1.f;
        dinvL[i] = rsqrtf(degL);
        dinvH[i] = rsqrtf(degH);
        dinvLL[i] = rsqrtf(degLL);
        dinvHH[i] = rsqrtf(degHH);
        diag1[i] = make_float2(1.f / degL, 1.f / degH);
        diag2[i] = make_float2(1.f / degLL, 1.f / degHH);
    }
}

// per-bucket CSR placement into the bucket's contiguous span of `sorted`
__global__ __launch_bounds__(256) void k_place(const u32* __restrict__ bentry,
                                               const u32* __restrict__ bbase,
                                               const int* __restrict__ rowptr, const int* __restrict__ mid,
                                               int* __restrict__ sorted, int n) {
    __shared__ int cur[256];
    int row = blockIdx.x * 128 + threadIdx.x;
    if (threadIdx.x < 128) {
        int rr = min(row, n - 1);
        cur[threadIdx.x] = rowptr[rr];       // L cursor (masked sources, front)
        cur[128 + threadIdx.x] = mid[rr];    // H cursor (unmasked, back)
    }
    __syncthreads();
    u32 s0 = bbase[blockIdx.x], s1 = bbase[blockIdx.x + 1];
    for (u32 i = s0 + threadIdx.x; i < s1; i += 256) {
        u32 e = bentry[i];
        int rl = e & 127;
        int col = (int)((e >> 7) & 0x1FFFF);
        int isH = (int)((e >> 31) ^ 1u);
        int pos = atomicAdd(&cur[rl + (isH << 7)], 1);
        sorted[pos] = col;
    }
}

// ---------------- SpMM layer 1 ----------------

__global__ __launch_bounds__(256) void spmm1(const u16* __restrict__ X,
                                             const int* __restrict__ rowptr, const int* __restrict__ sorted,
                                             const float* __restrict__ mask,
                                             const float* __restrict__ dinvL, const float* __restrict__ dinvH,
                                             const float2* __restrict__ diag1,
                                             u16* __restrict__ Yl, u16* __restrict__ Yh, int n) {
    int r = blockIdx.x * 4 + (threadIdx.x >> 6);
    if (r >= n) return;
    int lane = threadIdx.x & 63;
    int q = lane >> 4, l16 = lane & 15;
    bool mi = mask[r] != 0.f;
    const float* dinvA = mi ? dinvL : dinvH;
    float da = dinvA[r];
    float2 dg = diag1[r];
    float diag = mi ? dg.x : dg.y;

    const uint4* Xv = (const uint4*)X;
    uint4 xown = Xv[(size_t)r * 16 + l16];

    float acc[8] = {0.f, 0.f, 0.f, 0.f, 0.f, 0.f, 0.f, 0.f};
    int e0 = rowptr[r], e1 = rowptr[r + 1];
    int last = e1 - 1;
    for (int base = e0; base < e1; base += 8) {
        int s0 = base + q, s1 = base + 4 + q;
        int i0 = min(s0, last), i1 = min(s1, last);
        int c0 = sorted[i0], c1 = sorted[i1];
        float w0 = (s0 < e1) ? da * dinvA[c0] : 0.f;
        float w1 = (s1 < e1) ? da * dinvA[c1] : 0.f;
        uint4 x0 = Xv[(size_t)c0 * 16 + l16];
        uint4 x1 = Xv[(size_t)c1 * 16 + l16];
        fma8(acc, w0, x0);
        fma8(acc, w1, x1);
    }
#pragma unroll
    for (int k = 0; k < 8; k++) {
        acc[k] += __shfl_xor(acc[k], 16);
        acc[k] += __shfl_xor(acc[k], 32);
    }
    float2 o0 = unpack2(xown.x), o1 = unpack2(xown.y), o2 = unpack2(xown.z), o3 = unpack2(xown.w);
    uint4 res;
    res.x = pack2(acc[0] + diag * o0.x, acc[1] + diag * o0.y);
    res.y = pack2(acc[2] + diag * o1.x, acc[3] + diag * o1.y);
    res.z = pack2(acc[4] + diag * o2.x, acc[5] + diag * o2.y);
    res.w = pack2(acc[6] + diag * o3.x, acc[7] + diag * o3.y);
    uint4* Ya = (uint4*)(mi ? Yl : Yh);
    uint4* Yc = (uint4*)(mi ? Yh : Yl);
    if (q == 0) Ya[(size_t)r * 16 + l16] = res;
    if (q == 1) Yc[(size_t)r * 16 + l16] = xown;   // deg=1, diag=1 -> exact copy
}

// ---------------- SpMM layer 2: partitioned rows, two uniform phases ----------------

__global__ __launch_bounds__(256) void spmm2(const u16* __restrict__ XL, const u16* __restrict__ XH,
                                             const int* __restrict__ rowptr, const int* __restrict__ mid,
                                             const int* __restrict__ sorted,
                                             const float* __restrict__ dinvLL, const float* __restrict__ dinvHH,
                                             const float2* __restrict__ diag2,
                                             u16* __restrict__ Zl, u16* __restrict__ Zh, int n) {
    int r = blockIdx.x * 4 + (threadIdx.x >> 6);
    if (r >= n) return;
    int lane = threadIdx.x & 63;
    int q = lane >> 4, l16 = lane & 15;

    float dllr = dinvLL[r], dhhr = dinvHH[r];
    float2 dg = diag2[r];

    const uint4* XLv = (const uint4*)XL;
    const uint4* XHv = (const uint4*)XH;
    uint4 xlown = XLv[(size_t)r * 16 + l16];
    uint4 xhown = XHv[(size_t)r * 16 + l16];

    float accL[8] = {0.f, 0.f, 0.f, 0.f, 0.f, 0.f, 0.f, 0.f};
    float accH[8] = {0.f, 0.f, 0.f, 0.f, 0.f, 0.f, 0.f, 0.f};
    int e0 = rowptr[r], m = mid[r], e1 = rowptr[r + 1];

    int lastL = m - 1;
    for (int base = e0; base < m; base += 8) {
        int s0 = base + q, s1 = base + 4 + q;
        int i0 = min(s0, lastL), i1 = min(s1, lastL);
        int c0 = sorted[i0], c1 = sorted[i1];
        float w0 = (s0 < m) ? dllr * dinvLL[c0] : 0.f;
        float w1 = (s1 < m) ? dllr * dinvLL[c1] : 0.f;
        uint4 x0 = XLv[(size_t)c0 * 16 + l16];
        uint4 x1 = XLv[(size_t)c1 * 16 + l16];
        fma8(accL, w0, x0);
        fma8(accL, w1, x1);
    }
    int lastH = e1 - 1;
    for (int base = m; base < e1; base += 8) {
        int s0 = base + q, s1 = base + 4 + q;
        int i0 = min(s0, lastH), i1 = min(s1, lastH);
        int c0 = sorted[i0], c1 = sorted[i1];
        float w0 = (s0 < e1) ? dhhr * dinvHH[c0] : 0.f;
        float w1 = (s1 < e1) ? dhhr * dinvHH[c1] : 0.f;
        uint4 x0 = XHv[(size_t)c0 * 16 + l16];
        uint4 x1 = XHv[(size_t)c1 * 16 + l16];
        fma8(accH, w0, x0);
        fma8(accH, w1, x1);
    }
#pragma unroll
    for (int k = 0; k < 8; k++) {
        accL[k] += __shfl_xor(accL[k], 16);
        accL[k] += __shfl_xor(accL[k], 32);
        accH[k] += __shfl_xor(accH[k], 16);
        accH[k] += __shfl_xor(accH[k], 32);
    }
    float2 l0 = unpack2(xlown.x), l1 = unpack2(xlown.y), l2 = unpack2(xlown.z), l3 = unpack2(xlown.w);
    float2 h0 = unpack2(xhown.x), h1 = unpack2(xhown.y), h2 = unpack2(xhown.z), h3 = unpack2(xhown.w);
    float cl = dg.x, ch = dg.y;
    uint4 rl, rh;
    rl.x = pack2(accL[0] + cl * l0.x, accL[1] + cl * l0.y);
    rl.y = pack2(accL[2] + cl * l1.x, accL[3] + cl * l1.y);
    rl.z = pack2(accL[4] + cl * l2.x, accL[5] + cl * l2.y);
    rl.w = pack2(accL[6] + cl * l3.x, accL[7] + cl * l3.y);
    rh.x = pack2(accH[0] + ch * h0.x, accH[1] + ch * h0.y);
    rh.y = pack2(accH[2] + ch * h1.x, accH[3] + ch * h1.y);
    rh.z = pack2(accH[4] + ch * h2.x, accH[5] + ch * h2.y);
    rh.w = pack2(accH[6] + ch * h3.x, accH[7] + ch * h3.y);
    if (q == 0) ((uint4*)Zl)[(size_t)r * 16 + l16] = rl;
    if (q == 1) ((uint4*)Zh)[(size_t)r * 16 + l16] = rh;
}

// ---------------- weight transpose f32 -> bf16, lam folded into W2L/W2H ----------------

__global__ void transposeW(const float* __restrict__ W1L, const float* __restrict__ W1H,
                           const float* __restrict__ W2L, const float* __restrict__ W2H,
                           const float* __restrict__ WX,
                           const float* __restrict__ lam1, const float* __restrict__ lam2,
                           u16* __restrict__ Bt) {
    int w = blockIdx.x >> 6;
    int idx = (blockIdx.x & 63) * 256 + threadIdx.x;
    float scale = 1.f;
    if (w == 2) { float e0 = __expf(lam1[0]), e1 = __expf(lam1[1]); scale = e1 / (e0 + e1); }
    if (w == 3) { float f0 = __expf(lam2[0]), f1 = __expf(lam2[1]); scale = f1 / (f0 + f1); }
    const float* src = (w == 0) ? W1L : (w == 1) ? W1H : (w == 2) ? W2L : (w == 3) ? W2H : WX;
    int k = idx >> 7, nn = idx & 127;
    Bt[(size_t)w * 16384 + (size_t)nn * 128 + k] = f2bf(scale * src[idx]);
}

// ---------------- LDS-staged MFMA GEMM building blocks ----------------

typedef __attribute__((ext_vector_type(8))) short bf16x8;
typedef __attribute__((ext_vector_type(4))) float f32x4;

DI void stageB(const uint4* __restrict__ Bt4, uint4* Bs, int tid) {
#pragma unroll
    for (int i = 0; i < 8; i++) {
        int g = i * 256 + tid;
        int nn = g >> 4, c = g & 15;
        int d = ((nn >> 4) * 4 + (c >> 2)) * 64 + (c & 3) * 16 + (nn & 15);
        Bs[d] = Bt4[g];
    }
}

DI void loadA(uint4* a, const uint4* __restrict__ A4, int mr, int quad) {
#pragma unroll
    for (int kb = 0; kb < 4; kb++)
        a[kb] = A4[(size_t)mr * 16 + kb * 4 + quad];
}

DI void mfmaSec(const uint4* a, const uint4* Bs, f32x4* acc, int lane) {
#pragma unroll
    for (int nt = 0; nt < 8; nt++)
#pragma unroll
        for (int kb = 0; kb < 4; kb++) {
            bf16x8 av = *(const bf16x8*)&a[kb];
            bf16x8 bv = *(const bf16x8*)&Bs[(nt * 4 + kb) * 64 + lane];
            acc[nt] = __builtin_amdgcn_mfma_f32_16x16x32_bf16(av, bv, acc[nt], 0, 0, 0);
        }
}

// ---------------- layer-1 GEMM (2 jobs via blockIdx.y), relu, coalesced store ----------------

__global__ __launch_bounds__(256) void gemm_lds(const u16* __restrict__ A0, const u16* __restrict__ Bt0,
                                                u16* __restrict__ C0,
                                                const u16* __restrict__ A1, const u16* __restrict__ Bt1,
                                                u16* __restrict__ C1, int M) {
    __shared__ uint4 Bs[2048];
    const u16* A = blockIdx.y ? A1 : A0;
    const u16* Bt = blockIdx.y ? Bt1 : Bt0;
    u16* C = blockIdx.y ? C1 : C0;

    int tid = threadIdx.x;
    int wave = tid >> 6, lane = tid & 63, quad = lane >> 4, l16 = lane & 15;
    int tile = blockIdx.x * 64;
    int m0 = tile + wave * 16 + l16;
    int mr = min(m0, M - 1);

    uint4 a[4];
    loadA(a, (const uint4*)A, mr, quad);
    stageB((const uint4*)Bt, Bs, tid);
    __syncthreads();

    f32x4 acc[8];
#pragma unroll
    for (int nt = 0; nt < 8; nt++) acc[nt] = f32x4{0.f, 0.f, 0.f, 0.f};
    mfmaSec(a, Bs, acc, lane);

    __syncthreads();
    u16* Cs = (u16*)Bs;
    int lrow0 = wave * 16 + quad * 4;
#pragma unroll
    for (int nt = 0; nt < 8; nt++)
#pragma unroll
        for (int rr = 0; rr < 4; rr++) {
            float v = acc[nt][rr];
            v = v > 0.f ? v : 0.f;
            Cs[(lrow0 + rr) * 128 + nt * 16 + l16] = f2bf(v);
        }
    __syncthreads();
    uint4* Cs4 = (uint4*)Bs;
    uint4* C4 = (uint4*)C;
#pragma unroll
    for (int i = 0; i < 4; i++) {
        int g = i * 256 + tid;
        int grow = tile + (g >> 4);
        if (grow < M) C4[(size_t)grow * 16 + (g & 15)] = Cs4[g];
    }
}

// ---------------- fused final ----------------

__global__ __launch_bounds__(256) void fused_final(const u16* __restrict__ Zl, const u16* __restrict__ Zh,
                                                   const u16* __restrict__ Xb,
                                                   const u16* __restrict__ BtL, const u16* __restrict__ BtH,
                                                   const u16* __restrict__ BtX,
                                                   const float* __restrict__ mask,
                                                   const float* __restrict__ lam1, const float* __restrict__ lam2,
                                                   const float* __restrict__ lin_w, const float* __restrict__ lin_b,
                                                   float* __restrict__ out, int M) {
    __shared__ uint4 Bs[2048];
    __shared__ float lws[1280];

    int tid = threadIdx.x;
    int wave = tid >> 6, lane = tid & 63, quad = lane >> 4, l16 = lane & 15;
    int tile = blockIdx.x * 64;
    int m0 = tile + wave * 16 + l16;
    int mr = min(m0, M - 1);

    uint4 a[4], an[4];
    loadA(a, (const uint4*)Zl, mr, quad);
    {
        const uint4* lw4 = (const uint4*)lin_w;
        uint4* lws4 = (uint4*)lws;
        lws4[tid] = lw4[tid];
        if (tid < 64) lws4[256 + tid] = lw4[256 + tid];
    }
    stageB((const uint4*)BtL, Bs, tid);

    float e0 = __expf(lam1[0]), e1 = __expf(lam1[1]);
    float lamxl = e0 / (e0 + e1);
    float f0 = __expf(lam2[0]), f1 = __expf(lam2[1]);
    float lamxh = f0 / (f0 + f1);
    float lamx = (mask[mr] != 0.f) ? lamxl : lamxh;

    __syncthreads();

    f32x4 acc[8];
#pragma unroll
    for (int nt = 0; nt < 8; nt++) acc[nt] = f32x4{0.f, 0.f, 0.f, 0.f};

    loadA(an, (const uint4*)Zh, mr, quad);
    mfmaSec(a, Bs, acc, lane);

    __syncthreads();
    stageB((const uint4*)BtH, Bs, tid);
#pragma unroll
    for (int kb = 0; kb < 4; kb++) a[kb] = an[kb];
    loadA(an, (const uint4*)Xb, mr, quad);
    __syncthreads();
    mfmaSec(a, Bs, acc, lane);

    __syncthreads();
    stageB((const uint4*)BtX, Bs, tid);
#pragma unroll
    for (int kb = 0; kb < 4; kb++) a[kb] = scale8(an[kb], lamx);
    __syncthreads();
    mfmaSec(a, Bs, acc, lane);

    int rbase = tile + wave * 16 + quad * 4;
    float part[4][10];
#pragma unroll
    for (int rr = 0; rr < 4; rr++)
#pragma unroll
        for (int c = 0; c < 10; c++) part[rr][c] = 0.f;

#pragma unroll
    for (int nt = 0; nt < 8; nt++) {
        const float* lw = lws + (nt * 16 + l16) * 10;
        float lwv[10];
#pragma unroll
        for (int c = 0; c < 10; c++) lwv[c] = lw[c];
#pragma unroll
        for (int rr = 0; rr < 4; rr++) {
            float p = acc[nt][rr];
            p = p > 0.f ? p : 0.f;
#pragma unroll
            for (int c = 0; c < 10; c++) part[rr][c] += p * lwv[c];
        }
    }
#pragma unroll
    for (int rr = 0; rr < 4; rr++)
#pragma unroll
        for (int c = 0; c < 10; c++) {
            part[rr][c] += __shfl_xor(part[rr][c], 1);
            part[rr][c] += __shfl_xor(part[rr][c], 2);
            part[rr][c] += __shfl_xor(part[rr][c], 4);
            part[rr][c] += __shfl_xor(part[rr][c], 8);
        }
    if (l16 == 0) {
#pragma unroll
        for (int rr = 0; rr < 4; rr++) {
            int row = rbase + rr;
            if (row < M) {
#pragma unroll
                for (int c = 0; c < 10; c++)
                    out[(size_t)row * 10 + c] = part[rr][c] + lin_b[c];
            }
        }
    }
}

// ---------------- launch ----------------

extern "C" void kernel_launch(void* const* d_in, const int* in_sizes, int n_in,
                              void* d_out, int out_size, void* d_ws, size_t ws_size,
                              hipStream_t stream) {
    const float* x = (const float*)d_in[0];
    const int* ei = (const int*)d_in[1];
    const float* mask = (const float*)d_in[2];
    const float* W1L = (const float*)d_in[3];
    const float* W1H = (const float*)d_in[4];
    const float* W2L = (const float*)d_in[5];
    const float* W2H = (const float*)d_in[6];
    const float* WX = (const float*)d_in[7];
    const float* lam1 = (const float*)d_in[8];
    const float* lam2 = (const float*)d_in[9];
    const float* lin_w = (const float*)d_in[10];
    const float* lin_b = (const float*)d_in[11];
    float* out = (float*)d_out;

    int E = in_sizes[1] / 2;
    int n = in_sizes[2];
    int NB = (n + 127) >> 7;                   // 782 for n=100000 (<= NBPAD)
    int NBLK = (E + CHUNK - 1) / CHUNK;        // 196 for E=1.6M (<= 256)

    char* w = (char*)d_ws;
    size_t off = 0;
    auto alloc = [&](size_t bytes) -> void* {
        off = (off + 255) & ~(size_t)255;
        void* p = w + off;
        off += bytes;
        return p;
    };
    u32* cntP = (u32*)alloc((size_t)n * 4);
    u64* bits = (u64*)alloc((size_t)((n + 63) / 64 + 1) * 8);
    int* rowptr = (int*)alloc((size_t)(n + 1) * 4);
    int* midp = (int*)alloc((size_t)n * 4);
    int* blocksum = (int*)alloc(128 * 4);
    u32* hist2d = (u32*)alloc((size_t)NBLK * NBPAD * 4);
    u32* off2d = (u32*)alloc((size_t)NBLK * NBPAD * 4);
    u32* btotal = (u32*)alloc((size_t)NBPAD * 4);
    u32* bbase = (u32*)alloc((size_t)(NB + 1) * 4);
    u32* bentry = (u32*)alloc((size_t)E * 4);
    int* sorted = (int*)alloc((size_t)E * 4);
    float* dinvL = (float*)alloc((size_t)n * 4);
    float* dinvH = (float*)alloc((size_t)n * 4);
    float* dinvLL = (float*)alloc((size_t)n * 4);
    float* dinvHH = (float*)alloc((size_t)n * 4);
    float2* diag1 = (float2*)alloc((size_t)n * 8);
    float2* diag2 = (float2*)alloc((size_t)n * 8);
    u16* Bt = (u16*)alloc(5 * 16384 * 2);
    size_t actb = (size_t)n * 128 * 2;
    u16* Xb = (u16*)alloc(actb);
    u16* B0 = (u16*)alloc(actb);
    u16* B1 = (u16*)alloc(actb);
    u16* B2 = (u16*)alloc(actb);
    u16* B3 = (u16*)alloc(actb);

    int nblkScan = (n + SCAN_B - 1) / SCAN_B;
    int total4 = n * 128 / 4;
    int cvtBlocks = (total4 + 255) / 256;
    int maskBlocks = ((n + 63) / 64 + 3) / 4;

    pre_k<<<cvtBlocks + maskBlocks, 256, 0, stream>>>(x, Xb, total4, cvtBlocks, mask, bits, n);
    k_count<<<NBLK, 256, 0, stream>>>(ei, E, NB, hist2d);
    k_colscan<<<NB, 256, 0, stream>>>(hist2d, off2d, NBLK, btotal);
    k_basescan<<<1, 1024, 0, stream>>>(btotal, bbase, NB);
    k_scatter<<<NBLK, 256, 0, stream>>>(ei, E, NB, off2d, bbase, bits, bentry);
    k_rowhist<<<NB, 256, 0, stream>>>(bentry, bbase, cntP, n);
    scanA<<<nblkScan, 1024, 0, stream>>>(cntP, rowptr, blocksum, n);
    scanBC<<<nblkScan, 256, 0, stream>>>(blocksum, nblkScan, rowptr, cntP, mask, midp,
                                         dinvL, dinvH, dinvLL, dinvHH, diag1, diag2, n);
    k_place<<<NB, 256, 0, stream>>>(bentry, bbase, rowptr, midp, sorted, n);

    int rowsblk = (n + 3) / 4;
    int gemmblk = (n + 63) / 64;

    spmm1<<<rowsblk, 256, 0, stream>>>(Xb, rowptr, sorted, mask, dinvL, dinvH, diag1, B0, B1, n);
    transposeW<<<320, 256, 0, stream>>>(W1L, W1H, W2L, W2H, WX, lam1, lam2, Bt);
    gemm_lds<<<dim3(gemmblk, 2), 256, 0, stream>>>(B0, Bt + 0 * 16384, B2,
                                                   B1, Bt + 1 * 16384, B3, n);

    spmm2<<<rowsblk, 256, 0, stream>>>(B2, B3, rowptr, midp, sorted, dinvLL, dinvHH, diag2, B0, B1, n);

    fused_final<<<gemmblk, 256, 0, stream>>>(B0, B1, Xb,
                                             Bt + 2 * 16384, Bt + 3 * 16384, Bt + 4 * 16384,
                                             mask, lam1, lam2, lin_w, lin_b, out, n);
}

// Round 9
// 403.590 us; speedup vs baseline: 1.3246x; 1.0241x over previous
//
#include <hip/hip_runtime.h>
#include <stdint.h>

typedef unsigned int u32;
typedef unsigned short u16;
typedef unsigned long long u64;

#define DI __device__ __forceinline__

DI float bf2f(u16 u) { union { u32 i; float f; } v; v.i = ((u32)u) << 16; return v.f; }
DI u16 f2bf(float f) {
    union { u32 i; float f; } v; v.f = f;
    u32 u = v.i;
    u32 r = (u + 0x7fffu + ((u >> 16) & 1u)) >> 16;
    return (u16)r;
}
DI float2 unpack2(u32 x) { return make_float2(bf2f((u16)(x & 0xffffu)), bf2f((u16)(x >> 16))); }
DI u32 pack2(float a, float b) { return (u32)f2bf(a) | ((u32)f2bf(b) << 16); }

DI void fma8(float* acc, float w, uint4 xv) {
    float2 f0 = unpack2(xv.x), f1 = unpack2(xv.y), f2 = unpack2(xv.z), f3 = unpack2(xv.w);
    acc[0] += w * f0.x; acc[1] += w * f0.y; acc[2] += w * f1.x; acc[3] += w * f1.y;
    acc[4] += w * f2.x; acc[5] += w * f2.y; acc[6] += w * f3.x; acc[7] += w * f3.y;
}

DI uint4 scale8(uint4 v, float s) {
    uint4 r;
    float2 f;
    f = unpack2(v.x); r.x = pack2(f.x * s, f.y * s);
    f = unpack2(v.y); r.y = pack2(f.x * s, f.y * s);
    f = unpack2(v.z); r.z = pack2(f.x * s, f.y * s);
    f = unpack2(v.w); r.w = pack2(f.x * s, f.y * s);
    return r;
}

// ---------------- fused head: x->bf16 cvt | mask bits | transposeW | k_count ----------------

#define CHUNK 8192
#define NBPAD 800

__global__ __launch_bounds__(256) void head_k(const float* __restrict__ X, u16* __restrict__ Xb,
                                              int total4, int cvtBlocks, int maskBlocks,
                                              const float* __restrict__ mask, u64* __restrict__ bits, int n,
                                              const float* __restrict__ W1L, const float* __restrict__ W1H,
                                              const float* __restrict__ W2L, const float* __restrict__ W2H,
                                              const float* __restrict__ WX,
                                              const float* __restrict__ lam1, const float* __restrict__ lam2,
                                              u16* __restrict__ Bt,
                                              const int* __restrict__ ei, int E, int NB,
                                              u32* __restrict__ hist2d) {
    int bx = blockIdx.x;
    if (bx < cvtBlocks) {
        int i = bx * 256 + threadIdx.x;
        if (i >= total4) return;
        float4 v = ((const float4*)X)[i];
        ushort4 o;
        o.x = f2bf(v.x); o.y = f2bf(v.y); o.z = f2bf(v.z); o.w = f2bf(v.w);
        ((ushort4*)Xb)[i] = o;
        return;
    }
    bx -= cvtBlocks;
    if (bx < maskBlocks) {
        int i = bx * 256 + threadIdx.x;
        bool m = (i < n) && (mask[i] != 0.f);
        u64 word = __ballot(m);
        if ((threadIdx.x & 63) == 0 && i < n) bits[i >> 6] = word;
        return;
    }
    bx -= maskBlocks;
    if (bx < 320) {
        int w = bx >> 6;
        int idx = (bx & 63) * 256 + threadIdx.x;
        float scale = 1.f;
        if (w == 2) { float e0 = __expf(lam1[0]), e1 = __expf(lam1[1]); scale = e1 / (e0 + e1); }
        if (w == 3) { float f0 = __expf(lam2[0]), f1 = __expf(lam2[1]); scale = f1 / (f0 + f1); }
        const float* src = (w == 0) ? W1L : (w == 1) ? W1H : (w == 2) ? W2L : (w == 3) ? W2H : WX;
        int k = idx >> 7, nn = idx & 127;
        Bt[(size_t)w * 16384 + (size_t)nn * 128 + k] = f2bf(scale * src[idx]);
        return;
    }
    bx -= 320;
    // k_count
    __shared__ u32 hist[NBPAD];
    for (int i = threadIdx.x; i < NBPAD; i += 256) hist[i] = 0;
    __syncthreads();
    int base = bx * CHUNK;
    int end = min(base + CHUNK, E);
    for (int e = base + threadIdx.x; e < end; e += 256) {
        int c = ei[e], r = ei[E + e];
        if (r != c) atomicAdd(&hist[r >> 7], 1u);
    }
    __syncthreads();
    u32* out = hist2d + (size_t)bx * NBPAD;
    for (int i = threadIdx.x; i < NB; i += 256) out[i] = hist[i];
}

// per-bucket scan over the NBLK chunk-counts
__global__ __launch_bounds__(256) void k_colscan(const u32* __restrict__ hist2d,
                                                 u32* __restrict__ off2d,
                                                 int NBLK, u32* __restrict__ btotal) {
    __shared__ u32 s[256];
    int t = blockIdx.x;
    int k = threadIdx.x;
    u32 v = (k < NBLK) ? hist2d[(size_t)k * NBPAD + t] : 0;
    s[k] = v;
    __syncthreads();
    for (int off = 1; off < 256; off <<= 1) {
        u32 tmp = (k >= off) ? s[k - off] : 0;
        __syncthreads();
        s[k] += tmp;
        __syncthreads();
    }
    if (k < NBLK) off2d[(size_t)k * NBPAD + t] = s[k] - v;
    if (k == 0) btotal[t] = s[255];
}

__global__ __launch_bounds__(1024) void k_basescan(const u32* __restrict__ btotal,
                                                   u32* __restrict__ bbase, int NB) {
    __shared__ u32 s[1024];
    int t = threadIdx.x;
    u32 v = (t < NB) ? btotal[t] : 0;
    s[t] = v;
    __syncthreads();
    for (int off = 1; off < 1024; off <<= 1) {
        u32 tmp = (t >= off) ? s[t - off] : 0;
        __syncthreads();
        s[t] += tmp;
        __syncthreads();
    }
    if (t < NB) bbase[t] = s[t] - v;
    if (t == NB - 1) bbase[NB] = s[t];
}

// entry = row_low(7) | col<<7 (17) | maskbit<<31
__global__ __launch_bounds__(256) void k_scatter(const int* __restrict__ ei, int E, int NB,
                                                 const u32* __restrict__ off2d,
                                                 const u32* __restrict__ bbase,
                                                 const u64* __restrict__ bits,
                                                 u32* __restrict__ bentry) {
    __shared__ u32 cur[NBPAD];
    const u32* off = off2d + (size_t)blockIdx.x * NBPAD;
    for (int i = threadIdx.x; i < NB; i += 256) cur[i] = off[i] + bbase[i];
    __syncthreads();
    int base = blockIdx.x * CHUNK;
    int end = min(base + CHUNK, E);
    for (int e = base + threadIdx.x; e < end; e += 256) {
        int c = ei[e], r = ei[E + e];
        if (r != c) {
            u32 pos = atomicAdd(&cur[r >> 7], 1u);
            u32 m = (u32)((bits[c >> 6] >> (c & 63)) & 1);
            bentry[pos] = (u32)(r & 127) | ((u32)c << 7) | (m << 31);
        }
    }
}

// per-bucket dense row histogram -> cntP (lo16=cnt, hi16=cntm)
__global__ __launch_bounds__(256) void k_rowhist(const u32* __restrict__ bentry,
                                                 const u32* __restrict__ bbase,
                                                 u32* __restrict__ cntP, int n) {
    __shared__ u32 h[128];
    if (threadIdx.x < 128) h[threadIdx.x] = 0;
    __syncthreads();
    u32 s0 = bbase[blockIdx.x], s1 = bbase[blockIdx.x + 1];
    for (u32 i = s0 + threadIdx.x; i < s1; i += 256) {
        u32 e = bentry[i];
        atomicAdd(&h[e & 127], 1u + ((e >> 31) << 16));
    }
    __syncthreads();
    int row = blockIdx.x * 128 + threadIdx.x;
    if (threadIdx.x < 128 && row < n) cntP[row] = h[threadIdx.x];
}

#define SCAN_B 1024
__global__ __launch_bounds__(1024) void scanA(const u32* __restrict__ cntP, int* __restrict__ rowptr,
                                              int* __restrict__ blocksum, int n) {
    __shared__ int s[SCAN_B];
    int t = threadIdx.x;
    int i = blockIdx.x * SCAN_B + t;
    int v = (i < n) ? (int)(cntP[i] & 0xffffu) : 0;
    s[t] = v; __syncthreads();
    for (int off = 1; off < SCAN_B; off <<= 1) {
        int tmp = (t >= off) ? s[t - off] : 0;
        __syncthreads();
        s[t] += tmp;
        __syncthreads();
    }
    if (i < n) rowptr[i] = s[t] - v;
    if (t == SCAN_B - 1) blocksum[blockIdx.x] = s[t];
}

__global__ __launch_bounds__(256) void scanBC(const int* __restrict__ blocksum, int nblk,
                                              int* __restrict__ rowptr, const u32* __restrict__ cntP,
                                              const float* __restrict__ mask,
                                              int* __restrict__ mid,
                                              float* __restrict__ dinvL, float* __restrict__ dinvH,
                                              float* __restrict__ dinvLL, float* __restrict__ dinvHH,
                                              float2* __restrict__ diag1, float2* __restrict__ diag2, int n) {
    __shared__ int s[128];
    int t = threadIdx.x;
    if (t < 128) s[t] = (t < nblk) ? blocksum[t] : 0;
    __syncthreads();
    for (int off = 1; off < 128; off <<= 1) {
        int tmp = (t >= off && t < 128) ? s[t - off] : 0;
        __syncthreads();
        if (t < 128) s[t] += tmp;
        __syncthreads();
    }
    int blockoff = (blockIdx.x == 0) ? 0 : s[blockIdx.x - 1];
    if (blockIdx.x == 0 && t == 0) rowptr[n] = s[127];
#pragma unroll
    for (int k = 0; k < 4; k++) {
        int i = blockIdx.x * SCAN_B + k * 256 + t;
        if (i >= n) break;
        int v = rowptr[i] + blockoff;
        rowptr[i] = v;
        u32 p = cntP[i];
        int ci = (int)(p & 0xffffu);
        int cmi = (int)(p >> 16);
        mid[i] = v + cmi;
        float c = (float)ci;
        float cm = (float)cmi;
        bool mi = mask[i] != 0.f;
        float degL = (mi ? c : 0.f) + 1.f;
        float degH = (mi ? 0.f : c) + 1.f;
        float degLL = cm + 1.f;
        float degHH = (c - cm) + 1.f;
        dinvL[i] = rsqrtf(degL);
        dinvH[i] = rsqrtf(degH);
        dinvLL[i] = rsqrtf(degLL);
        dinvHH[i] = rsqrtf(degHH);
        diag1[i] = make_float2(1.f / degL, 1.f / degH);
        diag2[i] = make_float2(1.f / degLL, 1.f / degHH);
    }
}

// per-bucket CSR placement
__global__ __launch_bounds__(256) void k_place(const u32* __restrict__ bentry,
                                               const u32* __restrict__ bbase,
                                               const int* __restrict__ rowptr, const int* __restrict__ mid,
                                               int* __restrict__ sorted, int n) {
    __shared__ int cur[256];
    int row = blockIdx.x * 128 + threadIdx.x;
    if (threadIdx.x < 128) {
        int rr = min(row, n - 1);
        cur[threadIdx.x] = rowptr[rr];
        cur[128 + threadIdx.x] = mid[rr];
    }
    __syncthreads();
    u32 s0 = bbase[blockIdx.x], s1 = bbase[blockIdx.x + 1];
    for (u32 i = s0 + threadIdx.x; i < s1; i += 256) {
        u32 e = bentry[i];
        int rl = e & 127;
        int col = (int)((e >> 7) & 0x1FFFF);
        int isH = (int)((e >> 31) ^ 1u);
        int pos = atomicAdd(&cur[rl + (isH << 7)], 1);
        sorted[pos] = col;
    }
}

// ---------------- SpMM gather phase: exact full 4-edge bodies + one masked tail ----------------

DI void gather_phase(const uint4* __restrict__ Xv, const int* __restrict__ sorted,
                     const float* __restrict__ dinv, float dr,
                     int e0, int e1, int q, int l16, float* acc) {
    int len = e1 - e0;
    int nfull = len >> 2;
    int e = e0;
#pragma unroll 2
    for (int it = 0; it < nfull; it++) {
        int c = sorted[e + q];
        float w = dr * dinv[c];
        uint4 xv = Xv[(size_t)c * 16 + l16];
        fma8(acc, w, xv);
        e += 4;
    }
    int rem = len & 3;
    if (rem) {
        int idx = min(e + q, e1 - 1);
        int c = sorted[idx];
        float w = (q < rem) ? dr * dinv[c] : 0.f;
        uint4 xv = Xv[(size_t)c * 16 + l16];
        fma8(acc, w, xv);
    }
}

// ---------------- SpMM layer 1 ----------------

__global__ __launch_bounds__(256) void spmm1(const u16* __restrict__ X,
                                             const int* __restrict__ rowptr, const int* __restrict__ sorted,
                                             const float* __restrict__ mask,
                                             const float* __restrict__ dinvL, const float* __restrict__ dinvH,
                                             const float2* __restrict__ diag1,
                                             u16* __restrict__ Yl, u16* __restrict__ Yh, int n) {
    int r = blockIdx.x * 4 + (threadIdx.x >> 6);
    if (r >= n) return;
    int lane = threadIdx.x & 63;
    int q = lane >> 4, l16 = lane & 15;
    bool mi = mask[r] != 0.f;
    const float* dinvA = mi ? dinvL : dinvH;
    float da = dinvA[r];
    float2 dg = diag1[r];
    float diag = mi ? dg.x : dg.y;

    const uint4* Xv = (const uint4*)X;
    uint4 xown = Xv[(size_t)r * 16 + l16];

    float acc[8] = {0.f, 0.f, 0.f, 0.f, 0.f, 0.f, 0.f, 0.f};
    int e0 = rowptr[r], e1 = rowptr[r + 1];
    gather_phase(Xv, sorted, dinvA, da, e0, e1, q, l16, acc);

#pragma unroll
    for (int k = 0; k < 8; k++) {
        acc[k] += __shfl_xor(acc[k], 16);
        acc[k] += __shfl_xor(acc[k], 32);
    }
    float2 o0 = unpack2(xown.x), o1 = unpack2(xown.y), o2 = unpack2(xown.z), o3 = unpack2(xown.w);
    uint4 res;
    res.x = pack2(acc[0] + diag * o0.x, acc[1] + diag * o0.y);
    res.y = pack2(acc[2] + diag * o1.x, acc[3] + diag * o1.y);
    res.z = pack2(acc[4] + diag * o2.x, acc[5] + diag * o2.y);
    res.w = pack2(acc[6] + diag * o3.x, acc[7] + diag * o3.y);
    uint4* Ya = (uint4*)(mi ? Yl : Yh);
    uint4* Yc = (uint4*)(mi ? Yh : Yl);
    if (q == 0) Ya[(size_t)r * 16 + l16] = res;
    if (q == 1) Yc[(size_t)r * 16 + l16] = xown;   // deg=1, diag=1 -> exact copy
}

// ---------------- SpMM layer 2 ----------------

__global__ __launch_bounds__(256) void spmm2(const u16* __restrict__ XL, const u16* __restrict__ XH,
                                             const int* __restrict__ rowptr, const int* __restrict__ mid,
                                             const int* __restrict__ sorted,
                                             const float* __restrict__ dinvLL, const float* __restrict__ dinvHH,
                                             const float2* __restrict__ diag2,
                                             u16* __restrict__ Zl, u16* __restrict__ Zh, int n) {
    int r = blockIdx.x * 4 + (threadIdx.x >> 6);
    if (r >= n) return;
    int lane = threadIdx.x & 63;
    int q = lane >> 4, l16 = lane & 15;

    float dllr = dinvLL[r], dhhr = dinvHH[r];
    float2 dg = diag2[r];

    const uint4* XLv = (const uint4*)XL;
    const uint4* XHv = (const uint4*)XH;
    uint4 xlown = XLv[(size_t)r * 16 + l16];
    uint4 xhown = XHv[(size_t)r * 16 + l16];

    float accL[8] = {0.f, 0.f, 0.f, 0.f, 0.f, 0.f, 0.f, 0.f};
    float accH[8] = {0.f, 0.f, 0.f, 0.f, 0.f, 0.f, 0.f, 0.f};
    int e0 = rowptr[r], m = mid[r], e1 = rowptr[r + 1];

    gather_phase(XLv, sorted, dinvLL, dllr, e0, m, q, l16, accL);
    gather_phase(XHv, sorted, dinvHH, dhhr, m, e1, q, l16, accH);

#pragma unroll
    for (int k = 0; k < 8; k++) {
        accL[k] += __shfl_xor(accL[k], 16);
        accL[k] += __shfl_xor(accL[k], 32);
        accH[k] += __shfl_xor(accH[k], 16);
        accH[k] += __shfl_xor(accH[k], 32);
    }
    float2 l0 = unpack2(xlown.x), l1 = unpack2(xlown.y), l2 = unpack2(xlown.z), l3 = unpack2(xlown.w);
    float2 h0 = unpack2(xhown.x), h1 = unpack2(xhown.y), h2 = unpack2(xhown.z), h3 = unpack2(xhown.w);
    float cl = dg.x, ch = dg.y;
    uint4 rl, rh;
    rl.x = pack2(accL[0] + cl * l0.x, accL[1] + cl * l0.y);
    rl.y = pack2(accL[2] + cl * l1.x, accL[3] + cl * l1.y);
    rl.z = pack2(accL[4] + cl * l2.x, accL[5] + cl * l2.y);
    rl.w = pack2(accL[6] + cl * l3.x, accL[7] + cl * l3.y);
    rh.x = pack2(accH[0] + ch * h0.x, accH[1] + ch * h0.y);
    rh.y = pack2(accH[2] + ch * h1.x, accH[3] + ch * h1.y);
    rh.z = pack2(accH[4] + ch * h2.x, accH[5] + ch * h2.y);
    rh.w = pack2(accH[6] + ch * h3.x, accH[7] + ch * h3.y);
    if (q == 0) ((uint4*)Zl)[(size_t)r * 16 + l16] = rl;
    if (q == 1) ((uint4*)Zh)[(size_t)r * 16 + l16] = rh;
}

// ---------------- LDS-staged MFMA GEMM building blocks ----------------

typedef __attribute__((ext_vector_type(8))) short bf16x8;
typedef __attribute__((ext_vector_type(4))) float f32x4;

DI void stageB(const uint4* __restrict__ Bt4, uint4* Bs, int tid) {
#pragma unroll
    for (int i = 0; i < 8; i++) {
        int g = i * 256 + tid;
        int nn = g >> 4, c = g & 15;
        int d = ((nn >> 4) * 4 + (c >> 2)) * 64 + (c & 3) * 16 + (nn & 15);
        Bs[d] = Bt4[g];
    }
}

DI void loadA(uint4* a, const uint4* __restrict__ A4, int mr, int quad) {
#pragma unroll
    for (int kb = 0; kb < 4; kb++)
        a[kb] = A4[(size_t)mr * 16 + kb * 4 + quad];
}

DI void mfmaSec(const uint4* a, const uint4* Bs, f32x4* acc, int lane) {
#pragma unroll
    for (int nt = 0; nt < 8; nt++)
#pragma unroll
        for (int kb = 0; kb < 4; kb++) {
            bf16x8 av = *(const bf16x8*)&a[kb];
            bf16x8 bv = *(const bf16x8*)&Bs[(nt * 4 + kb) * 64 + lane];
            acc[nt] = __builtin_amdgcn_mfma_f32_16x16x32_bf16(av, bv, acc[nt], 0, 0, 0);
        }
}

// ---------------- layer-1 GEMM (2 jobs via blockIdx.y), relu, coalesced store ----------------

__global__ __launch_bounds__(256) void gemm_lds(const u16* __restrict__ A0, const u16* __restrict__ Bt0,
                                                u16* __restrict__ C0,
                                                const u16* __restrict__ A1, const u16* __restrict__ Bt1,
                                                u16* __restrict__ C1, int M) {
    __shared__ uint4 Bs[2048];
    const u16* A = blockIdx.y ? A1 : A0;
    const u16* Bt = blockIdx.y ? Bt1 : Bt0;
    u16* C = blockIdx.y ? C1 : C0;

    int tid = threadIdx.x;
    int wave = tid >> 6, lane = tid & 63, quad = lane >> 4, l16 = lane & 15;
    int tile = blockIdx.x * 64;
    int m0 = tile + wave * 16 + l16;
    int mr = min(m0, M - 1);

    uint4 a[4];
    loadA(a, (const uint4*)A, mr, quad);
    stageB((const uint4*)Bt, Bs, tid);
    __syncthreads();

    f32x4 acc[8];
#pragma unroll
    for (int nt = 0; nt < 8; nt++) acc[nt] = f32x4{0.f, 0.f, 0.f, 0.f};
    mfmaSec(a, Bs, acc, lane);

    __syncthreads();
    u16* Cs = (u16*)Bs;
    int lrow0 = wave * 16 + quad * 4;
#pragma unroll
    for (int nt = 0; nt < 8; nt++)
#pragma unroll
        for (int rr = 0; rr < 4; rr++) {
            float v = acc[nt][rr];
            v = v > 0.f ? v : 0.f;
            Cs[(lrow0 + rr) * 128 + nt * 16 + l16] = f2bf(v);
        }
    __syncthreads();
    uint4* Cs4 = (uint4*)Bs;
    uint4* C4 = (uint4*)C;
#pragma unroll
    for (int i = 0; i < 4; i++) {
        int g = i * 256 + tid;
        int grow = tile + (g >> 4);
        if (grow < M) C4[(size_t)grow * 16 + (g & 15)] = Cs4[g];
    }
}

// ---------------- fused final ----------------

__global__ __launch_bounds__(256) void fused_final(const u16* __restrict__ Zl, const u16* __restrict__ Zh,
                                                   const u16* __restrict__ Xb,
                                                   const u16* __restrict__ BtL, const u16* __restrict__ BtH,
                                                   const u16* __restrict__ BtX,
                                                   const float* __restrict__ mask,
                                                   const float* __restrict__ lam1, const float* __restrict__ lam2,
                                                   const float* __restrict__ lin_w, const float* __restrict__ lin_b,
                                                   float* __restrict__ out, int M) {
    __shared__ uint4 Bs[2048];
    __shared__ float lws[1280];

    int tid = threadIdx.x;
    int wave = tid >> 6, lane = tid & 63, quad = lane >> 4, l16 = lane & 15;
    int tile = blockIdx.x * 64;
    int m0 = tile + wave * 16 + l16;
    int mr = min(m0, M - 1);

    uint4 a[4], an[4];
    loadA(a, (const uint4*)Zl, mr, quad);
    {
        const uint4* lw4 = (const uint4*)lin_w;
        uint4* lws4 = (uint4*)lws;
        lws4[tid] = lw4[tid];
        if (tid < 64) lws4[256 + tid] = lw4[256 + tid];
    }
    stageB((const uint4*)BtL, Bs, tid);

    float e0 = __expf(lam1[0]), e1 = __expf(lam1[1]);
    float lamxl = e0 / (e0 + e1);
    float f0 = __expf(lam2[0]), f1 = __expf(lam2[1]);
    float lamxh = f0 / (f0 + f1);
    float lamx = (mask[mr] != 0.f) ? lamxl : lamxh;

    __syncthreads();

    f32x4 acc[8];
#pragma unroll
    for (int nt = 0; nt < 8; nt++) acc[nt] = f32x4{0.f, 0.f, 0.f, 0.f};

    loadA(an, (const uint4*)Zh, mr, quad);
    mfmaSec(a, Bs, acc, lane);

    __syncthreads();
    stageB((const uint4*)BtH, Bs, tid);
#pragma unroll
    for (int kb = 0; kb < 4; kb++) a[kb] = an[kb];
    loadA(an, (const uint4*)Xb, mr, quad);
    __syncthreads();
    mfmaSec(a, Bs, acc, lane);

    __syncthreads();
    stageB((const uint4*)BtX, Bs, tid);
#pragma unroll
    for (int kb = 0; kb < 4; kb++) a[kb] = scale8(an[kb], lamx);
    __syncthreads();
    mfmaSec(a, Bs, acc, lane);

    int rbase = tile + wave * 16 + quad * 4;
    float part[4][10];
#pragma unroll
    for (int rr = 0; rr < 4; rr++)
#pragma unroll
        for (int c = 0; c < 10; c++) part[rr][c] = 0.f;

#pragma unroll
    for (int nt = 0; nt < 8; nt++) {
        const float* lw = lws + (nt * 16 + l16) * 10;
        float lwv[10];
#pragma unroll
        for (int c = 0; c < 10; c++) lwv[c] = lw[c];
#pragma unroll
        for (int rr = 0; rr < 4; rr++) {
            float p = acc[nt][rr];
            p = p > 0.f ? p : 0.f;
#pragma unroll
            for (int c = 0; c < 10; c++) part[rr][c] += p * lwv[c];
        }
    }
#pragma unroll
    for (int rr = 0; rr < 4; rr++)
#pragma unroll
        for (int c = 0; c < 10; c++) {
            part[rr][c] += __shfl_xor(part[rr][c], 1);
            part[rr][c] += __shfl_xor(part[rr][c], 2);
            part[rr][c] += __shfl_xor(part[rr][c], 4);
            part[rr][c] += __shfl_xor(part[rr][c], 8);
        }
    if (l16 == 0) {
#pragma unroll
        for (int rr = 0; rr < 4; rr++) {
            int row = rbase + rr;
            if (row < M) {
#pragma unroll
                for (int c = 0; c < 10; c++)
                    out[(size_t)row * 10 + c] = part[rr][c] + lin_b[c];
            }
        }
    }
}

// ---------------- launch ----------------

extern "C" void kernel_launch(void* const* d_in, const int* in_sizes, int n_in,
                              void* d_out, int out_size, void* d_ws, size_t ws_size,
                              hipStream_t stream) {
    const float* x = (const float*)d_in[0];
    const int* ei = (const int*)d_in[1];
    const float* mask = (const float*)d_in[2];
    const float* W1L = (const float*)d_in[3];
    const float* W1H = (const float*)d_in[4];
    const float* W2L = (const float*)d_in[5];
    const float* W2H = (const float*)d_in[6];
    const float* WX = (const float*)d_in[7];
    const float* lam1 = (const float*)d_in[8];
    const float* lam2 = (const float*)d_in[9];
    const float* lin_w = (const float*)d_in[10];
    const float* lin_b = (const float*)d_in[11];
    float* out = (float*)d_out;

    int E = in_sizes[1] / 2;
    int n = in_sizes[2];
    int NB = (n + 127) >> 7;
    int NBLK = (E + CHUNK - 1) / CHUNK;

    char* w = (char*)d_ws;
    size_t off = 0;
    auto alloc = [&](size_t bytes) -> void* {
        off = (off + 255) & ~(size_t)255;
        void* p = w + off;
        off += bytes;
        return p;
    };
    u32* cntP = (u32*)alloc((size_t)n * 4);
    u64* bits = (u64*)alloc((size_t)((n + 63) / 64 + 1) * 8);
    int* rowptr = (int*)alloc((size_t)(n + 1) * 4);
    int* midp = (int*)alloc((size_t)n * 4);
    int* blocksum = (int*)alloc(128 * 4);
    u32* hist2d = (u32*)alloc((size_t)NBLK * NBPAD * 4);
    u32* off2d = (u32*)alloc((size_t)NBLK * NBPAD * 4);
    u32* btotal = (u32*)alloc((size_t)NBPAD * 4);
    u32* bbase = (u32*)alloc((size_t)(NB + 1) * 4);
    u32* bentry = (u32*)alloc((size_t)E * 4);
    int* sorted = (int*)alloc((size_t)E * 4);
    float* dinvL = (float*)alloc((size_t)n * 4);
    float* dinvH = (float*)alloc((size_t)n * 4);
    float* dinvLL = (float*)alloc((size_t)n * 4);
    float* dinvHH = (float*)alloc((size_t)n * 4);
    float2* diag1 = (float2*)alloc((size_t)n * 8);
    float2* diag2 = (float2*)alloc((size_t)n * 8);
    u16* Bt = (u16*)alloc(5 * 16384 * 2);
    size_t actb = (size_t)n * 128 * 2;
    u16* Xb = (u16*)alloc(actb);
    u16* B0 = (u16*)alloc(actb);
    u16* B1 = (u16*)alloc(actb);
    u16* B2 = (u16*)alloc(actb);
    u16* B3 = (u16*)alloc(actb);

    int nblkScan = (n + SCAN_B - 1) / SCAN_B;
    int total4 = n * 128 / 4;
    int cvtBlocks = (total4 + 255) / 256;
    int maskBlocks = ((n + 63) / 64 + 3) / 4;

    head_k<<<cvtBlocks + maskBlocks + 320 + NBLK, 256, 0, stream>>>(
        x, Xb, total4, cvtBlocks, maskBlocks, mask, bits, n,
        W1L, W1H, W2L, W2H, WX, lam1, lam2, Bt, ei, E, NB, hist2d);
    k_colscan<<<NB, 256, 0, stream>>>(hist2d, off2d, NBLK, btotal);
    k_basescan<<<1, 1024, 0, stream>>>(btotal, bbase, NB);
    k_scatter<<<NBLK, 256, 0, stream>>>(ei, E, NB, off2d, bbase, bits, bentry);
    k_rowhist<<<NB, 256, 0, stream>>>(bentry, bbase, cntP, n);
    scanA<<<nblkScan, 1024, 0, stream>>>(cntP, rowptr, blocksum, n);
    scanBC<<<nblkScan, 256, 0, stream>>>(blocksum, nblkScan, rowptr, cntP, mask, midp,
                                         dinvL, dinvH, dinvLL, dinvHH, diag1, diag2, n);
    k_place<<<NB, 256, 0, stream>>>(bentry, bbase, rowptr, midp, sorted, n);

    int rowsblk = (n + 3) / 4;
    int gemmblk = (n + 63) / 64;

    spmm1<<<rowsblk, 256, 0, stream>>>(Xb, rowptr, sorted, mask, dinvL, dinvH, diag1, B0, B1, n);
    gemm_lds<<<dim3(gemmblk, 2), 256, 0, stream>>>(B0, Bt + 0 * 16384, B2,
                                                   B1, Bt + 1 * 16384, B3, n);

    spmm2<<<rowsblk, 256, 0, stream>>>(B2, B3, rowptr, midp, sorted, dinvLL, dinvHH, diag2, B0, B1, n);

    fused_final<<<gemmblk, 256, 0, stream>>>(B0, B1, Xb,
                                             Bt + 2 * 16384, Bt + 3 * 16384, Bt + 4 * 16384,
                                             mask, lam1, lam2, lin_w, lin_b, out, n);
}

// Round 10
// 401.549 us; speedup vs baseline: 1.3313x; 1.0051x over previous
//
#include <hip/hip_runtime.h>
#include <hip/hip_fp16.h>
#include <stdint.h>

typedef unsigned int u32;
typedef unsigned short u16;
typedef unsigned long long u64;

#define DI __device__ __forceinline__

DI float bf2f(u16 u) { union { u32 i; float f; } v; v.i = ((u32)u) << 16; return v.f; }
DI u16 f2bf(float f) {
    union { u32 i; float f; } v; v.f = f;
    u32 u = v.i;
    u32 r = (u + 0x7fffu + ((u >> 16) & 1u)) >> 16;
    return (u16)r;
}
DI float2 unpack2(u32 x) { return make_float2(bf2f((u16)(x & 0xffffu)), bf2f((u16)(x >> 16))); }
DI u32 pack2(float a, float b) { return (u32)f2bf(a) | ((u32)f2bf(b) << 16); }

DI u16 f2h(float f) { __half h = __float2half_rn(f); return *(u16*)&h; }
DI float h2f(u16 u) { __half h; *(u16*)&h = u; return __half2float(h); }

DI void fma8(float* acc, float w, uint4 xv) {
    float2 f0 = unpack2(xv.x), f1 = unpack2(xv.y), f2 = unpack2(xv.z), f3 = unpack2(xv.w);
    acc[0] += w * f0.x; acc[1] += w * f0.y; acc[2] += w * f1.x; acc[3] += w * f1.y;
    acc[4] += w * f2.x; acc[5] += w * f2.y; acc[6] += w * f3.x; acc[7] += w * f3.y;
}

DI uint4 scale8(uint4 v, float s) {
    uint4 r;
    float2 f;
    f = unpack2(v.x); r.x = pack2(f.x * s, f.y * s);
    f = unpack2(v.y); r.y = pack2(f.x * s, f.y * s);
    f = unpack2(v.z); r.z = pack2(f.x * s, f.y * s);
    f = unpack2(v.w); r.w = pack2(f.x * s, f.y * s);
    return r;
}

DI int maskbit(const u64* __restrict__ bits, int i) {
    return (int)((bits[i >> 6] >> (i & 63)) & 1);
}

// ---------------- fused head: x->bf16 cvt | mask bits | transposeW | k_count ----------------

#define CHUNK 8192
#define NBPAD 800

__global__ __launch_bounds__(256) void head_k(const float* __restrict__ X, u16* __restrict__ Xb,
                                              int total4, int cvtBlocks, int maskBlocks,
                                              const float* __restrict__ mask, u64* __restrict__ bits, int n,
                                              const float* __restrict__ W1L, const float* __restrict__ W1H,
                                              const float* __restrict__ W2L, const float* __restrict__ W2H,
                                              const float* __restrict__ WX,
                                              const float* __restrict__ lam1, const float* __restrict__ lam2,
                                              u16* __restrict__ Bt,
                                              const int* __restrict__ ei, int E, int NB,
                                              u32* __restrict__ hist2d) {
    int bx = blockIdx.x;
    if (bx < cvtBlocks) {
        int i = bx * 256 + threadIdx.x;
        if (i >= total4) return;
        float4 v = ((const float4*)X)[i];
        ushort4 o;
        o.x = f2bf(v.x); o.y = f2bf(v.y); o.z = f2bf(v.z); o.w = f2bf(v.w);
        ((ushort4*)Xb)[i] = o;
        return;
    }
    bx -= cvtBlocks;
    if (bx < maskBlocks) {
        int i = bx * 256 + threadIdx.x;
        bool m = (i < n) && (mask[i] != 0.f);
        u64 word = __ballot(m);
        if ((threadIdx.x & 63) == 0 && i < n) bits[i >> 6] = word;
        return;
    }
    bx -= maskBlocks;
    if (bx < 320) {
        int w = bx >> 6;
        int idx = (bx & 63) * 256 + threadIdx.x;
        float scale = 1.f;
        if (w == 2) { float e0 = __expf(lam1[0]), e1 = __expf(lam1[1]); scale = e1 / (e0 + e1); }
        if (w == 3) { float f0 = __expf(lam2[0]), f1 = __expf(lam2[1]); scale = f1 / (f0 + f1); }
        const float* src = (w == 0) ? W1L : (w == 1) ? W1H : (w == 2) ? W2L : (w == 3) ? W2H : WX;
        int k = idx >> 7, nn = idx & 127;
        Bt[(size_t)w * 16384 + (size_t)nn * 128 + k] = f2bf(scale * src[idx]);
        return;
    }
    bx -= 320;
    // k_count
    __shared__ u32 hist[NBPAD];
    for (int i = threadIdx.x; i < NBPAD; i += 256) hist[i] = 0;
    __syncthreads();
    int base = bx * CHUNK;
    int end = min(base + CHUNK, E);
    for (int e = base + threadIdx.x; e < end; e += 256) {
        int c = ei[e], r = ei[E + e];
        if (r != c) atomicAdd(&hist[r >> 7], 1u);
    }
    __syncthreads();
    u32* out = hist2d + (size_t)bx * NBPAD;
    for (int i = threadIdx.x; i < NB; i += 256) out[i] = hist[i];
}

// per-bucket scan over the NBLK chunk-counts
__global__ __launch_bounds__(256) void k_colscan(const u32* __restrict__ hist2d,
                                                 u32* __restrict__ off2d,
                                                 int NBLK, u32* __restrict__ btotal) {
    __shared__ u32 s[256];
    int t = blockIdx.x;
    int k = threadIdx.x;
    u32 v = (k < NBLK) ? hist2d[(size_t)k * NBPAD + t] : 0;
    s[k] = v;
    __syncthreads();
    for (int off = 1; off < 256; off <<= 1) {
        u32 tmp = (k >= off) ? s[k - off] : 0;
        __syncthreads();
        s[k] += tmp;
        __syncthreads();
    }
    if (k < NBLK) off2d[(size_t)k * NBPAD + t] = s[k] - v;
    if (k == 0) btotal[t] = s[255];
}

__global__ __launch_bounds__(1024) void k_basescan(const u32* __restrict__ btotal,
                                                   u32* __restrict__ bbase, int NB) {
    __shared__ u32 s[1024];
    int t = threadIdx.x;
    u32 v = (t < NB) ? btotal[t] : 0;
    s[t] = v;
    __syncthreads();
    for (int off = 1; off < 1024; off <<= 1) {
        u32 tmp = (t >= off) ? s[t - off] : 0;
        __syncthreads();
        s[t] += tmp;
        __syncthreads();
    }
    if (t < NB) bbase[t] = s[t] - v;
    if (t == NB - 1) bbase[NB] = s[t];
}

// entry = row_low(7) | col<<7 (17) | maskbit<<31
__global__ __launch_bounds__(256) void k_scatter(const int* __restrict__ ei, int E, int NB,
                                                 const u32* __restrict__ off2d,
                                                 const u32* __restrict__ bbase,
                                                 const u64* __restrict__ bits,
                                                 u32* __restrict__ bentry) {
    __shared__ u32 cur[NBPAD];
    const u32* off = off2d + (size_t)blockIdx.x * NBPAD;
    for (int i = threadIdx.x; i < NB; i += 256) cur[i] = off[i] + bbase[i];
    __syncthreads();
    int base = blockIdx.x * CHUNK;
    int end = min(base + CHUNK, E);
    for (int e = base + threadIdx.x; e < end; e += 256) {
        int c = ei[e], r = ei[E + e];
        if (r != c) {
            u32 pos = atomicAdd(&cur[r >> 7], 1u);
            u32 m = (u32)((bits[c >> 6] >> (c & 63)) & 1);
            bentry[pos] = (u32)(r & 127) | ((u32)c << 7) | (m << 31);
        }
    }
}

// per-bucket dense row histogram -> cntP (lo16=cnt, hi16=cntm)
__global__ __launch_bounds__(256) void k_rowhist(const u32* __restrict__ bentry,
                                                 const u32* __restrict__ bbase,
                                                 u32* __restrict__ cntP, int n) {
    __shared__ u32 h[128];
    if (threadIdx.x < 128) h[threadIdx.x] = 0;
    __syncthreads();
    u32 s0 = bbase[blockIdx.x], s1 = bbase[blockIdx.x + 1];
    for (u32 i = s0 + threadIdx.x; i < s1; i += 256) {
        u32 e = bentry[i];
        atomicAdd(&h[e & 127], 1u + ((e >> 31) << 16));
    }
    __syncthreads();
    int row = blockIdx.x * 128 + threadIdx.x;
    if (threadIdx.x < 128 && row < n) cntP[row] = h[threadIdx.x];
}

#define SCAN_B 1024
__global__ __launch_bounds__(1024) void scanA(const u32* __restrict__ cntP, int* __restrict__ rowptr,
                                              int* __restrict__ blocksum, int n) {
    __shared__ int s[SCAN_B];
    int t = threadIdx.x;
    int i = blockIdx.x * SCAN_B + t;
    int v = (i < n) ? (int)(cntP[i] & 0xffffu) : 0;
    s[t] = v; __syncthreads();
    for (int off = 1; off < SCAN_B; off <<= 1) {
        int tmp = (t >= off) ? s[t - off] : 0;
        __syncthreads();
        s[t] += tmp;
        __syncthreads();
    }
    if (i < n) rowptr[i] = s[t] - v;
    if (t == SCAN_B - 1) blocksum[blockIdx.x] = s[t];
}

// finalize rowptr with block offsets
__global__ __launch_bounds__(256) void scanB2(const int* __restrict__ blocksum, int nblk,
                                              int* __restrict__ rowptr, int n) {
    __shared__ int s[128];
    int t = threadIdx.x;
    if (t < 128) s[t] = (t < nblk) ? blocksum[t] : 0;
    __syncthreads();
    for (int off = 1; off < 128; off <<= 1) {
        int tmp = (t >= off && t < 128) ? s[t - off] : 0;
        __syncthreads();
        if (t < 128) s[t] += tmp;
        __syncthreads();
    }
    int blockoff = (blockIdx.x == 0) ? 0 : s[blockIdx.x - 1];
    if (blockIdx.x == 0 && t == 0) rowptr[n] = s[127];
#pragma unroll
    for (int k = 0; k < 4; k++) {
        int i = blockIdx.x * SCAN_B + k * 256 + t;
        if (i < n) rowptr[i] += blockoff;
    }
}

// per-bucket CSR placement + per-edge weight precompute (fp16)
__global__ __launch_bounds__(256) void k_place(const u32* __restrict__ bentry,
                                               const u32* __restrict__ bbase,
                                               const int* __restrict__ rowptr,
                                               const u32* __restrict__ cntP,
                                               const u64* __restrict__ bits,
                                               int* __restrict__ sorted,
                                               u16* __restrict__ wgt1, u16* __restrict__ wgt2, int n) {
    __shared__ int cur[256];
    int row = blockIdx.x * 128 + threadIdx.x;
    if (threadIdx.x < 128) {
        int rr = min(row, n - 1);
        int rp = rowptr[rr];
        cur[threadIdx.x] = rp;                                // L cursor (masked sources, front)
        cur[128 + threadIdx.x] = rp + (int)(cntP[rr] >> 16);  // H cursor (mid)
    }
    __syncthreads();
    u32 s0 = bbase[blockIdx.x], s1 = bbase[blockIdx.x + 1];
    for (u32 i = s0 + threadIdx.x; i < s1; i += 256) {
        u32 e = bentry[i];
        int rl = e & 127;
        int col = (int)((e >> 7) & 0x1FFFF);
        u32 mc = e >> 31;                          // source mask bit
        int isH = (int)(mc ^ 1u);
        int pos = atomicAdd(&cur[rl + (isH << 7)], 1);
        int grow = blockIdx.x * 128 + rl;
        u32 mr = (u32)((bits[grow >> 6] >> (grow & 63)) & 1);
        u32 p = cntP[col];
        float cnt = (float)(p & 0xffffu), cm = (float)(p >> 16);
        // layer-1 weight: dinv of row's path at column c
        float w1 = (mc == mr) ? rsqrtf(cnt + 1.f) : 1.f;
        // layer-2 weight: phase dinv at column c
        float w2 = mc ? rsqrtf(cm + 1.f) : rsqrtf(cnt - cm + 1.f);
        sorted[pos] = col;
        wgt1[pos] = f2h(w1);
        wgt2[pos] = f2h(w2);
    }
}

// ---------------- SpMM gather phase: precomputed weights, full 4-edge bodies + masked tail ----------------

DI void gather_phase(const uint4* __restrict__ Xv, const int* __restrict__ cols,
                     const u16* __restrict__ wgts,
                     int e0, int e1, int q, int l16, float* acc) {
    int len = e1 - e0;
    int nfull = len >> 2;
    int e = e0;
#pragma unroll 2
    for (int it = 0; it < nfull; it++) {
        int c = cols[e + q];
        float w = h2f(wgts[e + q]);
        uint4 xv = Xv[(u32)(c * 16 + l16)];
        fma8(acc, w, xv);
        e += 4;
    }
    int rem = len & 3;
    if (rem) {
        int idx = min(e + q, e1 - 1);
        int c = cols[idx];
        float w = (q < rem) ? h2f(wgts[idx]) : 0.f;
        uint4 xv = Xv[(u32)(c * 16 + l16)];
        fma8(acc, w, xv);
    }
}

// ---------------- SpMM layer 1 (row factor hoisted; no copy write) ----------------

__global__ __launch_bounds__(256) void spmm1(const u16* __restrict__ X,
                                             const int* __restrict__ rowptr, const int* __restrict__ sorted,
                                             const u16* __restrict__ wgt1,
                                             const u64* __restrict__ bits, const u32* __restrict__ cntP,
                                             u16* __restrict__ Yl, u16* __restrict__ Yh, int n) {
    int r = blockIdx.x * 4 + (threadIdx.x >> 6);
    if (r >= n) return;
    int lane = threadIdx.x & 63;
    int q = lane >> 4, l16 = lane & 15;
    bool mi = maskbit(bits, r) != 0;
    float cnt = (float)(cntP[r] & 0xffffu);
    float da = rsqrtf(cnt + 1.f);     // row-side dinv (same value either path)
    float diag = da * da;             // 1/deg

    const uint4* Xv = (const uint4*)X;
    uint4 xown = Xv[(u32)(r * 16 + l16)];

    float acc[8] = {0.f, 0.f, 0.f, 0.f, 0.f, 0.f, 0.f, 0.f};
    int e0 = rowptr[r], e1 = rowptr[r + 1];
    gather_phase(Xv, sorted, wgt1, e0, e1, q, l16, acc);

#pragma unroll
    for (int k = 0; k < 8; k++) {
        acc[k] += __shfl_xor(acc[k], 16);
        acc[k] += __shfl_xor(acc[k], 32);
    }
    float2 o0 = unpack2(xown.x), o1 = unpack2(xown.y), o2 = unpack2(xown.z), o3 = unpack2(xown.w);
    uint4 res;
    res.x = pack2(da * acc[0] + diag * o0.x, da * acc[1] + diag * o0.y);
    res.y = pack2(da * acc[2] + diag * o1.x, da * acc[3] + diag * o1.y);
    res.z = pack2(da * acc[4] + diag * o2.x, da * acc[5] + diag * o2.y);
    res.w = pack2(da * acc[6] + diag * o3.x, da * acc[7] + diag * o3.y);
    uint4* Ya = (uint4*)(mi ? Yl : Yh);
    if (q == 0) Ya[(u32)(r * 16 + l16)] = res;
    // copy path (other matrix) = x[r] exactly; gemm reads Xb directly for those rows
}

// ---------------- SpMM layer 2 (row factors from cntP; weights precomputed) ----------------

__global__ __launch_bounds__(256) void spmm2(const u16* __restrict__ XL, const u16* __restrict__ XH,
                                             const int* __restrict__ rowptr, const int* __restrict__ sorted,
                                             const u16* __restrict__ wgt2, const u32* __restrict__ cntP,
                                             u16* __restrict__ Zl, u16* __restrict__ Zh, int n) {
    int r = blockIdx.x * 4 + (threadIdx.x >> 6);
    if (r >= n) return;
    int lane = threadIdx.x & 63;
    int q = lane >> 4, l16 = lane & 15;

    u32 p = cntP[r];
    float cnt = (float)(p & 0xffffu), cm = (float)(p >> 16);
    float dllr = rsqrtf(cm + 1.f);
    float dhhr = rsqrtf(cnt - cm + 1.f);
    float cl = dllr * dllr, ch = dhhr * dhhr;
    int e0 = rowptr[r], e1 = rowptr[r + 1];
    int m = e0 + (int)(p >> 16);

    const uint4* XLv = (const uint4*)XL;
    const uint4* XHv = (const uint4*)XH;
    uint4 xlown = XLv[(u32)(r * 16 + l16)];
    uint4 xhown = XHv[(u32)(r * 16 + l16)];

    float accL[8] = {0.f, 0.f, 0.f, 0.f, 0.f, 0.f, 0.f, 0.f};
    float accH[8] = {0.f, 0.f, 0.f, 0.f, 0.f, 0.f, 0.f, 0.f};

    gather_phase(XLv, sorted, wgt2, e0, m, q, l16, accL);
    gather_phase(XHv, sorted, wgt2, m, e1, q, l16, accH);

#pragma unroll
    for (int k = 0; k < 8; k++) {
        accL[k] += __shfl_xor(accL[k], 16);
        accL[k] += __shfl_xor(accL[k], 32);
        accH[k] += __shfl_xor(accH[k], 16);
        accH[k] += __shfl_xor(accH[k], 32);
    }
    float2 l0 = unpack2(xlown.x), l1 = unpack2(xlown.y), l2 = unpack2(xlown.z), l3 = unpack2(xlown.w);
    float2 h0 = unpack2(xhown.x), h1 = unpack2(xhown.y), h2 = unpack2(xhown.z), h3 = unpack2(xhown.w);
    uint4 rl, rh;
    rl.x = pack2(dllr * accL[0] + cl * l0.x, dllr * accL[1] + cl * l0.y);
    rl.y = pack2(dllr * accL[2] + cl * l1.x, dllr * accL[3] + cl * l1.y);
    rl.z = pack2(dllr * accL[4] + cl * l2.x, dllr * accL[5] + cl * l2.y);
    rl.w = pack2(dllr * accL[6] + cl * l3.x, dllr * accL[7] + cl * l3.y);
    rh.x = pack2(dhhr * accH[0] + ch * h0.x, dhhr * accH[1] + ch * h0.y);
    rh.y = pack2(dhhr * accH[2] + ch * h1.x, dhhr * accH[3] + ch * h1.y);
    rh.z = pack2(dhhr * accH[4] + ch * h2.x, dhhr * accH[5] + ch * h2.y);
    rh.w = pack2(dhhr * accH[6] + ch * h3.x, dhhr * accH[7] + ch * h3.y);
    if (q == 0) ((uint4*)Zl)[(u32)(r * 16 + l16)] = rl;
    if (q == 1) ((uint4*)Zh)[(u32)(r * 16 + l16)] = rh;
}

// ---------------- LDS-staged MFMA GEMM building blocks ----------------

typedef __attribute__((ext_vector_type(8))) short bf16x8;
typedef __attribute__((ext_vector_type(4))) float f32x4;

DI void stageB(const uint4* __restrict__ Bt4, uint4* Bs, int tid) {
#pragma unroll
    for (int i = 0; i < 8; i++) {
        int g = i * 256 + tid;
        int nn = g >> 4, c = g & 15;
        int d = ((nn >> 4) * 4 + (c >> 2)) * 64 + (c & 3) * 16 + (nn & 15);
        Bs[d] = Bt4[g];
    }
}

DI void loadA(uint4* a, const uint4* __restrict__ A4, int mr, int quad) {
#pragma unroll
    for (int kb = 0; kb < 4; kb++)
        a[kb] = A4[(size_t)mr * 16 + kb * 4 + quad];
}

DI void mfmaSec(const uint4* a, const uint4* Bs, f32x4* acc, int lane) {
#pragma unroll
    for (int nt = 0; nt < 8; nt++)
#pragma unroll
        for (int kb = 0; kb < 4; kb++) {
            bf16x8 av = *(const bf16x8*)&a[kb];
            bf16x8 bv = *(const bf16x8*)&Bs[(nt * 4 + kb) * 64 + lane];
            acc[nt] = __builtin_amdgcn_mfma_f32_16x16x32_bf16(av, bv, acc[nt], 0, 0, 0);
        }
}

// ---------------- layer-1 GEMM (2 jobs), per-row A-source select (gathered vs Xb) ----------------

__global__ __launch_bounds__(256) void gemm_lds(const u16* __restrict__ A0, const u16* __restrict__ Bt0,
                                                u16* __restrict__ C0,
                                                const u16* __restrict__ A1, const u16* __restrict__ Bt1,
                                                u16* __restrict__ C1,
                                                const u16* __restrict__ Xb, const u64* __restrict__ bits,
                                                int M) {
    __shared__ uint4 Bs[2048];
    int job = blockIdx.y;
    const u16* A = job ? A1 : A0;
    const u16* Bt = job ? Bt1 : Bt0;
    u16* C = job ? C1 : C0;

    int tid = threadIdx.x;
    int wave = tid >> 6, lane = tid & 63, quad = lane >> 4, l16 = lane & 15;
    int tile = blockIdx.x * 64;
    int m0 = tile + wave * 16 + l16;
    int mr = min(m0, M - 1);

    // row r gathered into Yl iff mask=1 (job0 reads Yl); into Yh iff mask=0 (job1).
    int mi = maskbit(bits, mr);
    bool useGathered = job ? (mi == 0) : (mi != 0);
    const uint4* src = useGathered ? (const uint4*)A : (const uint4*)Xb;

    uint4 a[4];
    loadA(a, src, mr, quad);
    stageB((const uint4*)Bt, Bs, tid);
    __syncthreads();

    f32x4 acc[8];
#pragma unroll
    for (int nt = 0; nt < 8; nt++) acc[nt] = f32x4{0.f, 0.f, 0.f, 0.f};
    mfmaSec(a, Bs, acc, lane);

    __syncthreads();
    u16* Cs = (u16*)Bs;
    int lrow0 = wave * 16 + quad * 4;
#pragma unroll
    for (int nt = 0; nt < 8; nt++)
#pragma unroll
        for (int rr = 0; rr < 4; rr++) {
            float v = acc[nt][rr];
            v = v > 0.f ? v : 0.f;
            Cs[(lrow0 + rr) * 128 + nt * 16 + l16] = f2bf(v);
        }
    __syncthreads();
    uint4* Cs4 = (uint4*)Bs;
    uint4* C4 = (uint4*)C;
#pragma unroll
    for (int i = 0; i < 4; i++) {
        int g = i * 256 + tid;
        int grow = tile + (g >> 4);
        if (grow < M) C4[(size_t)grow * 16 + (g & 15)] = Cs4[g];
    }
}

// ---------------- fused final ----------------

__global__ __launch_bounds__(256) void fused_final(const u16* __restrict__ Zl, const u16* __restrict__ Zh,
                                                   const u16* __restrict__ Xb,
                                                   const u16* __restrict__ BtL, const u16* __restrict__ BtH,
                                                   const u16* __restrict__ BtX,
                                                   const float* __restrict__ mask,
                                                   const float* __restrict__ lam1, const float* __restrict__ lam2,
                                                   const float* __restrict__ lin_w, const float* __restrict__ lin_b,
                                                   float* __restrict__ out, int M) {
    __shared__ uint4 Bs[2048];
    __shared__ float lws[1280];

    int tid = threadIdx.x;
    int wave = tid >> 6, lane = tid & 63, quad = lane >> 4, l16 = lane & 15;
    int tile = blockIdx.x * 64;
    int m0 = tile + wave * 16 + l16;
    int mr = min(m0, M - 1);

    uint4 a[4], an[4];
    loadA(a, (const uint4*)Zl, mr, quad);
    {
        const uint4* lw4 = (const uint4*)lin_w;
        uint4* lws4 = (uint4*)lws;
        lws4[tid] = lw4[tid];
        if (tid < 64) lws4[256 + tid] = lw4[256 + tid];
    }
    stageB((const uint4*)BtL, Bs, tid);

    float e0 = __expf(lam1[0]), e1 = __expf(lam1[1]);
    float lamxl = e0 / (e0 + e1);
    float f0 = __expf(lam2[0]), f1 = __expf(lam2[1]);
    float lamxh = f0 / (f0 + f1);
    float lamx = (mask[mr] != 0.f) ? lamxl : lamxh;

    __syncthreads();

    f32x4 acc[8];
#pragma unroll
    for (int nt = 0; nt < 8; nt++) acc[nt] = f32x4{0.f, 0.f, 0.f, 0.f};

    loadA(an, (const uint4*)Zh, mr, quad);
    mfmaSec(a, Bs, acc, lane);

    __syncthreads();
    stageB((const uint4*)BtH, Bs, tid);
#pragma unroll
    for (int kb = 0; kb < 4; kb++) a[kb] = an[kb];
    loadA(an, (const uint4*)Xb, mr, quad);
    __syncthreads();
    mfmaSec(a, Bs, acc, lane);

    __syncthreads();
    stageB((const uint4*)BtX, Bs, tid);
#pragma unroll
    for (int kb = 0; kb < 4; kb++) a[kb] = scale8(an[kb], lamx);
    __syncthreads();
    mfmaSec(a, Bs, acc, lane);

    int rbase = tile + wave * 16 + quad * 4;
    float part[4][10];
#pragma unroll
    for (int rr = 0; rr < 4; rr++)
#pragma unroll
        for (int c = 0; c < 10; c++) part[rr][c] = 0.f;

#pragma unroll
    for (int nt = 0; nt < 8; nt++) {
        const float* lw = lws + (nt * 16 + l16) * 10;
        float lwv[10];
#pragma unroll
        for (int c = 0; c < 10; c++) lwv[c] = lw[c];
#pragma unroll
        for (int rr = 0; rr < 4; rr++) {
            float p = acc[nt][rr];
            p = p > 0.f ? p : 0.f;
#pragma unroll
            for (int c = 0; c < 10; c++) part[rr][c] += p * lwv[c];
        }
    }
#pragma unroll
    for (int rr = 0; rr < 4; rr++)
#pragma unroll
        for (int c = 0; c < 10; c++) {
            part[rr][c] += __shfl_xor(part[rr][c], 1);
            part[rr][c] += __shfl_xor(part[rr][c], 2);
            part[rr][c] += __shfl_xor(part[rr][c], 4);
            part[rr][c] += __shfl_xor(part[rr][c], 8);
        }
    if (l16 == 0) {
#pragma unroll
        for (int rr = 0; rr < 4; rr++) {
            int row = rbase + rr;
            if (row < M) {
#pragma unroll
                for (int c = 0; c < 10; c++)
                    out[(size_t)row * 10 + c] = part[rr][c] + lin_b[c];
            }
        }
    }
}

// ---------------- launch ----------------

extern "C" void kernel_launch(void* const* d_in, const int* in_sizes, int n_in,
                              void* d_out, int out_size, void* d_ws, size_t ws_size,
                              hipStream_t stream) {
    const float* x = (const float*)d_in[0];
    const int* ei = (const int*)d_in[1];
    const float* mask = (const float*)d_in[2];
    const float* W1L = (const float*)d_in[3];
    const float* W1H = (const float*)d_in[4];
    const float* W2L = (const float*)d_in[5];
    const float* W2H = (const float*)d_in[6];
    const float* WX = (const float*)d_in[7];
    const float* lam1 = (const float*)d_in[8];
    const float* lam2 = (const float*)d_in[9];
    const float* lin_w = (const float*)d_in[10];
    const float* lin_b = (const float*)d_in[11];
    float* out = (float*)d_out;

    int E = in_sizes[1] / 2;
    int n = in_sizes[2];
    int NB = (n + 127) >> 7;
    int NBLK = (E + CHUNK - 1) / CHUNK;

    char* w = (char*)d_ws;
    size_t off = 0;
    auto alloc = [&](size_t bytes) -> void* {
        off = (off + 255) & ~(size_t)255;
        void* p = w + off;
        off += bytes;
        return p;
    };
    u32* cntP = (u32*)alloc((size_t)n * 4);
    u64* bits = (u64*)alloc((size_t)((n + 63) / 64 + 1) * 8);
    int* rowptr = (int*)alloc((size_t)(n + 1) * 4);
    int* blocksum = (int*)alloc(128 * 4);
    u32* hist2d = (u32*)alloc((size_t)NBLK * NBPAD * 4);
    u32* off2d = (u32*)alloc((size_t)NBLK * NBPAD * 4);
    u32* btotal = (u32*)alloc((size_t)NBPAD * 4);
    u32* bbase = (u32*)alloc((size_t)(NB + 1) * 4);
    u32* bentry = (u32*)alloc((size_t)E * 4);
    int* sorted = (int*)alloc((size_t)E * 4);
    u16* wgt1 = (u16*)alloc((size_t)E * 2);
    u16* wgt2 = (u16*)alloc((size_t)E * 2);
    u16* Bt = (u16*)alloc(5 * 16384 * 2);
    size_t actb = (size_t)n * 128 * 2;
    u16* Xb = (u16*)alloc(actb);
    u16* B0 = (u16*)alloc(actb);
    u16* B1 = (u16*)alloc(actb);
    u16* B2 = (u16*)alloc(actb);
    u16* B3 = (u16*)alloc(actb);

    int nblkScan = (n + SCAN_B - 1) / SCAN_B;
    int total4 = n * 128 / 4;
    int cvtBlocks = (total4 + 255) / 256;
    int maskBlocks = ((n + 63) / 64 + 3) / 4;

    head_k<<<cvtBlocks + maskBlocks + 320 + NBLK, 256, 0, stream>>>(
        x, Xb, total4, cvtBlocks, maskBlocks, mask, bits, n,
        W1L, W1H, W2L, W2H, WX, lam1, lam2, Bt, ei, E, NB, hist2d);
    k_colscan<<<NB, 256, 0, stream>>>(hist2d, off2d, NBLK, btotal);
    k_basescan<<<1, 1024, 0, stream>>>(btotal, bbase, NB);
    k_scatter<<<NBLK, 256, 0, stream>>>(ei, E, NB, off2d, bbase, bits, bentry);
    k_rowhist<<<NB, 256, 0, stream>>>(bentry, bbase, cntP, n);
    scanA<<<nblkScan, 1024, 0, stream>>>(cntP, rowptr, blocksum, n);
    scanB2<<<nblkScan, 256, 0, stream>>>(blocksum, nblkScan, rowptr, n);
    k_place<<<NB, 256, 0, stream>>>(bentry, bbase, rowptr, cntP, bits, sorted, wgt1, wgt2, n);

    int rowsblk = (n + 3) / 4;
    int gemmblk = (n + 63) / 64;

    spmm1<<<rowsblk, 256, 0, stream>>>(Xb, rowptr, sorted, wgt1, bits, cntP, B0, B1, n);
    gemm_lds<<<dim3(gemmblk, 2), 256, 0, stream>>>(B0, Bt + 0 * 16384, B2,
                                                   B1, Bt + 1 * 16384, B3, Xb, bits, n);

    spmm2<<<rowsblk, 256, 0, stream>>>(B2, B3, rowptr, sorted, wgt2, cntP, B0, B1, n);

    fused_final<<<gemmblk, 256, 0, stream>>>(B0, B1, Xb,
                                             Bt + 2 * 16384, Bt + 3 * 16384, Bt + 4 * 16384,
                                             mask, lam1, lam2, lin_w, lin_b, out, n);
}